// Round 17
// baseline (606.184 us; speedup 1.0000x reference)
//
#include <hip/hip_runtime.h>
#include <math.h>

#define N_USERS    200000
#define N_ITEMS    50000
#define N_ENTITIES 150000
#define N_EDGES    2000000
#define N_INTER    1000000
#define D          64

// scan decomposition: chunks of 1250 keys over concatenated key space e|c|r
#define CHUNK      1250
#define THR_OWN    5        // 250 active threads * 5 = 1250
#define NBLK_E     120      // 150000 / 1250
#define NBLK_C     40       //  50000 / 1250
#define NBLK_R     160      // 200000 / 1250
#define NBLK_TOT   (NBLK_E + NBLK_C + NBLK_R)   // 320

// LDS-binned histogram: key ranges x slices (NO global atomics).
// RK=8192 (32 KB LDS) -> 5 blocks/CU occupancy (r16's RK=16384 capped at 2).
#define RK     8192         // keys per range (32 KB LDS)
#define NS     16           // slices per index array
#define NR_E   19           // ceil(150000/8192)
#define NR_C   7            // ceil( 50000/8192)
#define NR_R   25           // ceil(200000/8192)
#define NR_TOT (NR_E + NR_C + NR_R)             // 51
#define KTOT   (N_ENTITIES + N_ITEMS + N_USERS) // 400000

// merged agg kernel block split
#define EB     2048         // blocks for edge role
#define IB     1024         // blocks for inter role

// fuse GEMM tiling
#define FT    64            // items per tile
#define FPAD  132           // LDS row stride in floats (128 + 4)
#define NTILE ((N_ITEMS + FT - 1) / FT)   // 782

// ---- bf16 helpers (tables are bf16; all accumulation stays fp32) ----
__device__ __forceinline__ unsigned short f2bf(float f) {
    unsigned u = __float_as_uint(f);
    u += 0x7FFFu + ((u >> 16) & 1u);       // round-to-nearest-even
    return (unsigned short)(u >> 16);
}
__device__ __forceinline__ ushort4 f2bf4(float4 f) {
    ushort4 o;
    o.x = f2bf(f.x); o.y = f2bf(f.y); o.z = f2bf(f.z); o.w = f2bf(f.w);
    return o;
}
__device__ __forceinline__ float4 bf2f4(ushort4 h) {
    float4 f;
    f.x = __uint_as_float(((unsigned)h.x) << 16);
    f.y = __uint_as_float(((unsigned)h.y) << 16);
    f.z = __uint_as_float(((unsigned)h.z) << 16);
    f.w = __uint_as_float(((unsigned)h.w) << 16);
    return f;
}

// sum across the 16 lanes of a quarter (offsets 1..8 stay inside quarter)
__device__ __forceinline__ float qsum16(float v) {
#pragma unroll
    for (int off = 1; off < 16; off <<= 1) v += __shfl_xor(v, off, 64);
    return v;
}

// ---- cvt fp32->bf16 tables + pack tail|type<<18 (one streaming kernel) ----
__global__ void prep_k(const float4* __restrict__ a, ushort4* __restrict__ ab, int na4,
                       const float4* __restrict__ b, ushort4* __restrict__ bb, int nb4,
                       const int* __restrict__ tail, const int* __restrict__ type,
                       int* __restrict__ packed) {
    int n = na4 + nb4 + N_EDGES;
    for (int i = blockIdx.x * blockDim.x + threadIdx.x; i < n;
         i += gridDim.x * blockDim.x) {
        if (i < na4) ab[i] = f2bf4(a[i]);
        else if (i < na4 + nb4) bb[i - na4] = f2bf4(b[i - na4]);
        else {
            int j = i - na4 - nb4;
            packed[j] = tail[j] | (type[j] << 18);
        }
    }
}

// resolve range -> (source array geometry) for hist
__device__ __forceinline__ void range_geom(int r, const int*& src, int& n,
                                           int& base, int& cbase, int& rlen,
                                           const int* head, const int* mcol,
                                           const int* mrow) {
    if (r < NR_E) {
        src = head; n = N_EDGES; base = r * RK; cbase = 0;
        rlen = N_ENTITIES - base;
    } else if (r < NR_E + NR_C) {
        src = mcol; n = N_INTER; base = (r - NR_E) * RK;
        cbase = N_ENTITIES; rlen = N_ITEMS - base;
    } else {
        src = mrow; n = N_INTER; base = (r - NR_E - NR_C) * RK;
        cbase = N_ENTITIES + N_ITEMS; rlen = N_USERS - base;
    }
    if (rlen > RK) rlen = RK;
}

// ---- hist: per-(range,slice) LDS histogram -> partial[s][key], AND record
// each element's rank within its (slice,key) cell (the LDS atomicAdd return
// value, free). Ranks make the later scatter 100% atomic-free. Per-(s,key)
// counts are ~Poisson(1): ushort is unconditionally safe. ----
__global__ void hist_part_k(const int* __restrict__ head,
                            const int* __restrict__ mcol,
                            const int* __restrict__ mrow,
                            int* __restrict__ partial,
                            unsigned short* __restrict__ rank_e,
                            unsigned short* __restrict__ rank_c,
                            unsigned short* __restrict__ rank_r) {
    __shared__ int lh[RK];
    int r = blockIdx.x >> 4, s = blockIdx.x & (NS - 1);
    for (int d = threadIdx.x; d < RK; d += 256) lh[d] = 0;
    __syncthreads();
    const int* src; int n, base, cbase, rlen;
    range_geom(r, src, n, base, cbase, rlen, head, mcol, mrow);
    unsigned short* rank = (r < NR_E) ? rank_e
                         : (r < NR_E + NR_C) ? rank_c : rank_r;
    int chunk = n / NS;
    int lo = s * chunk, hi = lo + chunk;
    int i = lo + threadIdx.x;
    for (; i + 768 < hi; i += 1024) {   // 4-way MLP on L3-resident reads
        unsigned d0 = (unsigned)(__builtin_nontemporal_load(&src[i])       - base);
        unsigned d1 = (unsigned)(__builtin_nontemporal_load(&src[i + 256]) - base);
        unsigned d2 = (unsigned)(__builtin_nontemporal_load(&src[i + 512]) - base);
        unsigned d3 = (unsigned)(__builtin_nontemporal_load(&src[i + 768]) - base);
        if (d0 < (unsigned)RK) rank[i]       = (unsigned short)atomicAdd(&lh[d0], 1);
        if (d1 < (unsigned)RK) rank[i + 256] = (unsigned short)atomicAdd(&lh[d1], 1);
        if (d2 < (unsigned)RK) rank[i + 512] = (unsigned short)atomicAdd(&lh[d2], 1);
        if (d3 < (unsigned)RK) rank[i + 768] = (unsigned short)atomicAdd(&lh[d3], 1);
    }
    for (; i < hi; i += 256) {
        unsigned d = (unsigned)(__builtin_nontemporal_load(&src[i]) - base);
        if (d < (unsigned)RK) rank[i] = (unsigned short)atomicAdd(&lh[d], 1);
    }
    __syncthreads();
    int* dst = partial + (size_t)s * KTOT + cbase + base;
    for (int d = threadIdx.x; d < rlen; d += 256) dst[d] = lh[d];
}

// ---- scan stage A: per-chunk sums of key totals (sum over slices) ----
__global__ void scanA_k(const int* __restrict__ partial,
                        int* __restrict__ blk_sums) {
    __shared__ int ss[256];
    int b = blockIdx.x, t = threadIdx.x;
    int base = b * CHUNK;
    int sum = 0;
    if (t < 250) {
        int g = base + t * THR_OWN;
#pragma unroll
        for (int s = 0; s < NS; ++s) {
            const int* p = partial + (size_t)s * KTOT + g;
#pragma unroll
            for (int j = 0; j < THR_OWN; ++j) sum += p[j];
        }
    }
    ss[t] = sum;
    __syncthreads();
    for (int off = 128; off > 0; off >>= 1) {
        if (t < off) ss[t] += ss[t + off];
        __syncthreads();
    }
    if (t == 0) blk_sums[b] = ss[0];
}

// ---- scan stage B: single block scans 320 partials, segment-reset ----
__global__ void scanB_k(int* __restrict__ blk_sums, int* __restrict__ blk_off,
                        int* __restrict__ e_starts, int* __restrict__ c_starts,
                        int* __restrict__ r_starts) {
    __shared__ int ss[512];
    int t = threadIdx.x;
    ss[t] = (t < NBLK_TOT) ? blk_sums[t] : 0;
    __syncthreads();
    for (int off = 1; off < 512; off <<= 1) {
        int v = (t >= off) ? ss[t - off] : 0;
        __syncthreads();
        ss[t] += v;   // inclusive scan
        __syncthreads();
    }
    if (t < NBLK_TOT) {
        int excl = (t == 0) ? 0 : ss[t - 1];
        int segstart_excl;
        if (t < NBLK_E) segstart_excl = 0;
        else if (t < NBLK_E + NBLK_C) segstart_excl = ss[NBLK_E - 1];
        else segstart_excl = ss[NBLK_E + NBLK_C - 1];
        blk_off[t] = excl - segstart_excl;
    }
    if (t == 0) {
        e_starts[N_ENTITIES] = N_EDGES;
        c_starts[N_ITEMS]    = N_INTER;
        r_starts[N_USERS]    = N_INTER;
    }
}

// ---- scan stage C: write starts[key]; transform partial[s][key] in place
// into the (slice,key) cursor start = starts[key] + sum_{s'<s} partial ----
__global__ void scanC_k(int* __restrict__ partial,
                        const int* __restrict__ blk_off,
                        int* __restrict__ e_starts, int* __restrict__ c_starts,
                        int* __restrict__ r_starts) {
    __shared__ int ss[256];
    int b = blockIdx.x, t = threadIdx.x;
    int base = b * CHUNK;
    int tot[THR_OWN];
    int sum = 0;
    if (t < 250) {
        int g = base + t * THR_OWN;
#pragma unroll
        for (int j = 0; j < THR_OWN; ++j) tot[j] = 0;
#pragma unroll
        for (int s = 0; s < NS; ++s) {
            const int* p = partial + (size_t)s * KTOT + g;
#pragma unroll
            for (int j = 0; j < THR_OWN; ++j) tot[j] += p[j];
        }
#pragma unroll
        for (int j = 0; j < THR_OWN; ++j) sum += tot[j];
    }
    ss[t] = sum;
    __syncthreads();
    for (int off = 1; off < 256; off <<= 1) {
        int v = (t >= off) ? ss[t - off] : 0;
        __syncthreads();
        ss[t] += v;
        __syncthreads();
    }
    if (t < 250) {
        int run = blk_off[b] + ((t == 0) ? 0 : ss[t - 1]);
        int* sarr; int ebase;
        if (b < NBLK_E)               { sarr = e_starts; ebase = base; }
        else if (b < NBLK_E + NBLK_C) { sarr = c_starts; ebase = base - NBLK_E * CHUNK; }
        else                          { sarr = r_starts; ebase = base - (NBLK_E + NBLK_C) * CHUNK; }
        int gl = ebase + t * THR_OWN;
        int gg = base + t * THR_OWN;
        for (int j = 0; j < THR_OWN; ++j) {
            sarr[gl + j] = run;
            int cur = run;
#pragma unroll
            for (int s = 0; s < NS; ++s) {
                int idx = s * KTOT + gg + j;
                int v = partial[idx];
                partial[idx] = cur;
                cur += v;
            }
            run = cur;
        }
    }
}

// ---- scatter: ZERO atomics. pos = cursor[s][key] + rank[i]. XCD key-range
// partitioned (proven r13 store-locality form), full occupancy. ----
__global__ void scatter_e_k(const int* __restrict__ head,
                            const int* __restrict__ packed,
                            const unsigned short* __restrict__ rank_e,
                            const int* __restrict__ partial,
                            int* __restrict__ e_sorted) {
    int xcd = blockIdx.x & 7;
    int slot = blockIdx.x >> 3;
    int nslot = gridDim.x >> 3;
    int lo = xcd * (N_ENTITIES / 8);
    int hi = lo + (N_ENTITIES / 8);
    for (int i = slot * blockDim.x + threadIdx.x; i < N_EDGES;
         i += nslot * blockDim.x) {
        int h = __builtin_nontemporal_load(&head[i]);
        if (h >= lo && h < hi) {
            int s = i / (N_EDGES / NS);
            int pos = partial[(size_t)s * KTOT + h]
                    + (int)__builtin_nontemporal_load(&rank_e[i]);
            e_sorted[pos] = __builtin_nontemporal_load(&packed[i]);
        }
    }
}

__global__ void scatter_i_k(const int* __restrict__ mcol,
                            const int* __restrict__ mrow,
                            const unsigned short* __restrict__ rank_c,
                            const unsigned short* __restrict__ rank_r,
                            const int* __restrict__ partial,
                            int* __restrict__ i_srow, int* __restrict__ i_scol) {
    int xcd = blockIdx.x & 7;
    int slot = blockIdx.x >> 3;
    int nslot = gridDim.x >> 3;
    int clo = xcd * (N_ITEMS / 8), chi = clo + (N_ITEMS / 8);
    int rlo = xcd * (N_USERS / 8), rhi = rlo + (N_USERS / 8);
    for (int i = slot * blockDim.x + threadIdx.x; i < N_INTER;
         i += nslot * blockDim.x) {
        int c = __builtin_nontemporal_load(&mcol[i]);
        int r = __builtin_nontemporal_load(&mrow[i]);
        int s = i / (N_INTER / NS);
        if (c >= clo && c < chi) {
            int pos = partial[(size_t)s * KTOT + N_ENTITIES + c]
                    + (int)__builtin_nontemporal_load(&rank_c[i]);
            i_srow[pos] = r;
        }
        if (r >= rlo && r < rhi) {
            int pos = partial[(size_t)s * KTOT + N_ENTITIES + N_ITEMS + r]
                    + (int)__builtin_nontemporal_load(&rank_r[i]);
            i_scol[pos] = c;
        }
    }
}

// ---- merged aggregation, QUARTER-PER-ROW: each 16-lane quarter owns one
// row entirely (16 lanes x ushort4 = full 128B bf16 row). Per-quarter loop
// divergence is safe: every __shfl source (lane&48)|k stays inside the
// quarter's own (active) lanes. ----
__global__ void agg_all_k(const ushort4* __restrict__ ent_bf,
                          const float* __restrict__ ent0f,
                          const float* __restrict__ wrel,
                          const int* __restrict__ es,
                          const int* __restrict__ e_sorted,
                          float* __restrict__ agg,
                          ushort4* __restrict__ ent_cur_bf,
                          float* __restrict__ ent_res,
                          const ushort4* __restrict__ usr_bf,
                          const int* __restrict__ cs,
                          const int* __restrict__ i_srow,
                          float* __restrict__ iint,
                          int first) {
    int lane = threadIdx.x & 63;
    int q = lane >> 4, ql = lane & 15;
    int qb = lane & 48;
    if (blockIdx.x < EB) {
        __shared__ float4 wl4[32 * 16];   // 32 relations x 16 float4 (fp32)
        for (int idx = threadIdx.x; idx < 512; idx += 256)
            wl4[idx] = ((const float4*)wrel)[idx];
        __syncthreads();
        int qid = (blockIdx.x * 4 + (threadIdx.x >> 6)) * 4 + q;
        int nq = EB * 16;
        for (int h = qid; h < N_ENTITIES; h += nq) {
            int beg = es[h], end = es[h + 1];
            float4 a0 = {0, 0, 0, 0}, a1 = {0, 0, 0, 0};
            for (int j0 = beg; j0 < end; j0 += 16) {
                int p = (j0 + ql < end) ? e_sorted[j0 + ql] : 0;
                int mm = end - j0; if (mm > 16) mm = 16;
                int k = 0;
                for (; k + 1 < mm; k += 2) {
                    int p0 = __shfl(p, qb | k, 64);
                    int p1 = __shfl(p, qb | (k + 1), 64);
                    float4 e0 = bf2f4(ent_bf[(size_t)(p0 & 0x3FFFF) * 16 + ql]);
                    float4 w0 = wl4[((p0 >> 18) << 4) + ql];
                    float4 e1 = bf2f4(ent_bf[(size_t)(p1 & 0x3FFFF) * 16 + ql]);
                    float4 w1 = wl4[((p1 >> 18) << 4) + ql];
                    a0.x = fmaf(e0.x, w0.x, a0.x); a0.y = fmaf(e0.y, w0.y, a0.y);
                    a0.z = fmaf(e0.z, w0.z, a0.z); a0.w = fmaf(e0.w, w0.w, a0.w);
                    a1.x = fmaf(e1.x, w1.x, a1.x); a1.y = fmaf(e1.y, w1.y, a1.y);
                    a1.z = fmaf(e1.z, w1.z, a1.z); a1.w = fmaf(e1.w, w1.w, a1.w);
                }
                if (k < mm) {
                    int p0 = __shfl(p, qb | k, 64);
                    float4 e0 = bf2f4(ent_bf[(size_t)(p0 & 0x3FFFF) * 16 + ql]);
                    float4 w0 = wl4[((p0 >> 18) << 4) + ql];
                    a0.x = fmaf(e0.x, w0.x, a0.x); a0.y = fmaf(e0.y, w0.y, a0.y);
                    a0.z = fmaf(e0.z, w0.z, a0.z); a0.w = fmaf(e0.w, w0.w, a0.w);
                }
            }
            float4 v; v.x = a0.x + a1.x; v.y = a0.y + a1.y;
            v.z = a0.z + a1.z; v.w = a0.w + a1.w;
            if (h < N_ITEMS) {
                int d = end - beg;
                float inv = 1.0f / (float)(d > 0 ? d : 1);
                float4 o; o.x = v.x * inv; o.y = v.y * inv;
                o.z = v.z * inv; o.w = v.w * inv;
                ((float4*)agg)[(size_t)h * 16 + ql] = o;
            } else {
                // l2norm(mean) == l2norm(sum): scale-invariant
                float s = qsum16(fmaf(v.x, v.x, fmaf(v.y, v.y, fmaf(v.z, v.z, v.w * v.w))));
                float inv = 1.0f / fmaxf(sqrtf(s), 1e-12f);
                float4 vn; vn.x = v.x * inv; vn.y = v.y * inv;
                vn.z = v.z * inv; vn.w = v.w * inv;
                size_t o4 = (size_t)h * 16 + ql;
                if (first) {
                    ent_cur_bf[o4] = f2bf4(vn);
                    float4 b = ((const float4*)ent0f)[o4];
                    b.x += vn.x; b.y += vn.y; b.z += vn.z; b.w += vn.w;
                    ((float4*)ent_res)[o4] = b;
                } else {
                    float4 r = ((float4*)ent_res)[o4];
                    r.x += vn.x; r.y += vn.y; r.z += vn.z; r.w += vn.w;
                    ((float4*)ent_res)[o4] = r;
                }
            }
        }
    } else {
        int qid = ((blockIdx.x - EB) * 4 + (threadIdx.x >> 6)) * 4 + q;
        int nq = IB * 16;
        for (int c = qid; c < N_ITEMS; c += nq) {
            int beg = cs[c], end = cs[c + 1];
            float4 a0 = {0, 0, 0, 0}, a1 = {0, 0, 0, 0};
            for (int j0 = beg; j0 < end; j0 += 16) {
                int p = (j0 + ql < end) ? i_srow[j0 + ql] : 0;
                int mm = end - j0; if (mm > 16) mm = 16;
                int k = 0;
                for (; k + 1 < mm; k += 2) {
                    int p0 = __shfl(p, qb | k, 64);
                    int p1 = __shfl(p, qb | (k + 1), 64);
                    float4 u0 = bf2f4(usr_bf[(size_t)p0 * 16 + ql]);
                    float4 u1 = bf2f4(usr_bf[(size_t)p1 * 16 + ql]);
                    a0.x += u0.x; a0.y += u0.y; a0.z += u0.z; a0.w += u0.w;
                    a1.x += u1.x; a1.y += u1.y; a1.z += u1.z; a1.w += u1.w;
                }
                if (k < mm) {
                    int p0 = __shfl(p, qb | k, 64);
                    float4 u0 = bf2f4(usr_bf[(size_t)p0 * 16 + ql]);
                    a0.x += u0.x; a0.y += u0.y; a0.z += u0.z; a0.w += u0.w;
                }
            }
            float4 v; v.x = a0.x + a1.x; v.y = a0.y + a1.y;
            v.z = a0.z + a1.z; v.w = a0.w + a1.w;
            int d = end - beg;
            float inv = 1.0f / (float)(d > 0 ? d : 1);
            float4 o; o.x = v.x * inv; o.y = v.y * inv;
            o.z = v.z * inv; o.w = v.w * inv;
            ((float4*)iint)[(size_t)c * 16 + ql] = o;
        }
    }
}

// ---- fuse: register-tiled LDS GEMM, y = [kg|ii] @ [g1|g2]^T ----
// outputs: ifus_bf + ent_cur_bf (bf16 gather tables), fp32 residuals.
__global__ void fuse_k(const float* __restrict__ agg,
                       const float* __restrict__ iint,
                       const float* __restrict__ g1,
                       const float* __restrict__ g2,
                       const float* __restrict__ ent0,
                       unsigned short* __restrict__ ifus_bf,
                       unsigned short* __restrict__ ent_cur_bf,
                       float* __restrict__ ent_res,
                       float* __restrict__ kg_res,
                       float* __restrict__ int_res,
                       int first) {
    __shared__ float A[FT * FPAD];   // [item][k]: k 0..63 = kg, 64..127 = ii
    __shared__ float B[64 * FPAD];   // [j][k]:    k 0..63 = g1, 64..127 = g2
    int t = threadIdx.x;
    int ibase = blockIdx.x * FT;

    {
        const float4* g14 = (const float4*)g1;
        const float4* g24 = (const float4*)g2;
        const float4* a4 = (const float4*)(agg + (size_t)ibase * D);
        const float4* i4 = (const float4*)(iint + (size_t)ibase * D);
        for (int idx = t; idx < 1024; idx += 256) {
            int r = idx >> 4, kq = idx & 15;
            ((float4*)&B[r * FPAD])[kq]      = g14[idx];
            ((float4*)&B[r * FPAD + 64])[kq] = g24[idx];
            ((float4*)&A[r * FPAD])[kq]      = a4[idx];   // benign OOB read on
            ((float4*)&A[r * FPAD + 64])[kq] = i4[idx];   // tail tile (ws mem)
        }
    }
    __syncthreads();

    int ti = t >> 4, tj = t & 15;

    float y[4][4] = {};
    for (int k = 0; k < 128; k += 4) {
        float4 av[4], bv[4];
#pragma unroll
        for (int a = 0; a < 4; ++a) av[a] = *(const float4*)&A[(ti + 16 * a) * FPAD + k];
#pragma unroll
        for (int b = 0; b < 4; ++b) bv[b] = *(const float4*)&B[(tj + 16 * b) * FPAD + k];
#pragma unroll
        for (int a = 0; a < 4; ++a)
#pragma unroll
            for (int b = 0; b < 4; ++b) {
                y[a][b] = fmaf(av[a].x, bv[b].x, y[a][b]);
                y[a][b] = fmaf(av[a].y, bv[b].y, y[a][b]);
                y[a][b] = fmaf(av[a].z, bv[b].z, y[a][b]);
                y[a][b] = fmaf(av[a].w, bv[b].w, y[a][b]);
            }
    }

    float fus[4][4], kg[4][4], ii[4][4];
    float sf[4], sk[4], si[4];
#pragma unroll
    for (int a = 0; a < 4; ++a) { sf[a] = 0.f; sk[a] = 0.f; si[a] = 0.f; }
#pragma unroll
    for (int a = 0; a < 4; ++a) {
        int i = ti + 16 * a;
#pragma unroll
        for (int b = 0; b < 4; ++b) {
            int j = tj + 16 * b;
            float K = A[i * FPAD + j];
            float I = A[i * FPAD + 64 + j];
            float gi = 1.0f / (1.0f + __expf(-y[a][b]));
            float f = gi * K + (1.0f - gi) * I;
            fus[a][b] = f; kg[a][b] = K; ii[a][b] = I;
            sf[a] = fmaf(f, f, sf[a]);
            sk[a] = fmaf(K, K, sk[a]);
            si[a] = fmaf(I, I, si[a]);
        }
    }
#pragma unroll
    for (int off = 1; off < 16; off <<= 1) {
#pragma unroll
        for (int a = 0; a < 4; ++a) {
            sf[a] += __shfl_xor(sf[a], off, 64);
            sk[a] += __shfl_xor(sk[a], off, 64);
            si[a] += __shfl_xor(si[a], off, 64);
        }
    }

#pragma unroll
    for (int a = 0; a < 4; ++a) {
        int i = ibase + ti + 16 * a;
        if (i < N_ITEMS) {
            float nf = 1.0f / fmaxf(sqrtf(sf[a]), 1e-12f);
            float nk = 1.0f / fmaxf(sqrtf(sk[a]), 1e-12f);
            float ni = 1.0f / fmaxf(sqrtf(si[a]), 1e-12f);
#pragma unroll
            for (int b = 0; b < 4; ++b) {
                size_t o = (size_t)i * D + tj + 16 * b;
                float f = fus[a][b];
                ifus_bf[o] = f2bf(f);
                float fn = f * nf;
                ent_cur_bf[o] = f2bf(fn);
                if (first) {
                    ent_res[o] = ent0[o] + fn;
                    kg_res[o]  = kg[a][b] * nk;
                    int_res[o] = ii[a][b] * ni;
                } else {
                    ent_res[o] += fn;
                    kg_res[o]  += kg[a][b] * nk;
                    int_res[o] += ii[a][b] * ni;
                }
            }
        }
    }
}

// ---- per-user segment sum of item_fusion + l2 norm (quarter-per-row) ----
__global__ void user_agg_k(const ushort4* __restrict__ ifus_bf,
                           const int* __restrict__ rs,
                           const int* __restrict__ i_scol,
                           const float* __restrict__ usr0,
                           ushort4* __restrict__ usr_cur_bf,
                           float* __restrict__ usr_res,
                           int first) {
    const float4* u04 = (const float4*)usr0;
    int lane = threadIdx.x & 63;
    int q = lane >> 4, ql = lane & 15;
    int qb = lane & 48;
    int qid = (blockIdx.x * (blockDim.x >> 6) + (threadIdx.x >> 6)) * 4 + q;
    int nq = gridDim.x * (blockDim.x >> 6) * 4;
    for (int u = qid; u < N_USERS; u += nq) {
        int beg = rs[u], end = rs[u + 1];
        float4 a0 = {0, 0, 0, 0}, a1 = {0, 0, 0, 0};
        for (int j0 = beg; j0 < end; j0 += 16) {
            int p = (j0 + ql < end) ? i_scol[j0 + ql] : 0;
            int mm = end - j0; if (mm > 16) mm = 16;
            int k = 0;
            for (; k + 1 < mm; k += 2) {
                int p0 = __shfl(p, qb | k, 64);
                int p1 = __shfl(p, qb | (k + 1), 64);
                float4 u0 = bf2f4(ifus_bf[(size_t)p0 * 16 + ql]);
                float4 u1 = bf2f4(ifus_bf[(size_t)p1 * 16 + ql]);
                a0.x += u0.x; a0.y += u0.y; a0.z += u0.z; a0.w += u0.w;
                a1.x += u1.x; a1.y += u1.y; a1.z += u1.z; a1.w += u1.w;
            }
            if (k < mm) {
                int p0 = __shfl(p, qb | k, 64);
                float4 u0 = bf2f4(ifus_bf[(size_t)p0 * 16 + ql]);
                a0.x += u0.x; a0.y += u0.y; a0.z += u0.z; a0.w += u0.w;
            }
        }
        float4 v; v.x = a0.x + a1.x; v.y = a0.y + a1.y;
        v.z = a0.z + a1.z; v.w = a0.w + a1.w;
        float s = qsum16(fmaf(v.x, v.x, fmaf(v.y, v.y, fmaf(v.z, v.z, v.w * v.w))));
        float inv = 1.0f / fmaxf(sqrtf(s), 1e-12f);
        float4 vn; vn.x = v.x * inv; vn.y = v.y * inv;
        vn.z = v.z * inv; vn.w = v.w * inv;
        size_t o4 = (size_t)u * 16 + ql;
        usr_cur_bf[o4] = f2bf4(vn);
        if (first) {
            float4 b = u04[o4];
            b.x += vn.x; b.y += vn.y; b.z += vn.z; b.w += vn.w;
            ((float4*)usr_res)[o4] = b;
        } else {
            float4 r = ((float4*)usr_res)[o4];
            r.x += vn.x; r.y += vn.y; r.z += vn.z; r.w += vn.w;
            ((float4*)usr_res)[o4] = r;
        }
    }
}

extern "C" void kernel_launch(void* const* d_in, const int* in_sizes, int n_in,
                              void* d_out, int out_size, void* d_ws, size_t ws_size,
                              hipStream_t stream) {
    const float* user_emb   = (const float*)d_in[0];
    const float* entity_emb = (const float*)d_in[1];
    const float* wrel       = (const float*)d_in[2];
    const float* g1         = (const float*)d_in[3];
    const float* g2         = (const float*)d_in[4];
    const int*   edge_head  = (const int*)d_in[5];
    const int*   edge_tail  = (const int*)d_in[6];
    const int*   edge_type  = (const int*)d_in[7];
    const int*   mat_row    = (const int*)d_in[8];
    const int*   mat_col    = (const int*)d_in[9];

    const size_t ENT_SZ = (size_t)N_ENTITIES * D;  //  9.6M
    const size_t USR_SZ = (size_t)N_USERS * D;     // 12.8M
    const size_t ITM_SZ = (size_t)N_ITEMS * D;     //  3.2M

    float* out     = (float*)d_out;
    float* ent_res = out;
    float* usr_res = out + ENT_SZ;
    float* kg_res  = out + ENT_SZ + USR_SZ;
    float* int_res = out + ENT_SZ + USR_SZ + ITM_SZ;

    // workspace layout (bf16 gather tables + fp32 staging)
    char* p = (char*)d_ws;
    unsigned short* ent_cur_bf = (unsigned short*)p; p += ENT_SZ * 2;  // 19.2 MB
    unsigned short* usr_cur_bf = (unsigned short*)p; p += USR_SZ * 2;  // 25.6 MB
    unsigned short* ent0_bf    = (unsigned short*)p; p += ENT_SZ * 2;  // 19.2 MB
    unsigned short* usr0_bf    = (unsigned short*)p; p += USR_SZ * 2;  // 25.6 MB
    float* agg  = (float*)p; p += ITM_SZ * 4;                          // 12.8 MB
    float* iint = (float*)p; p += ITM_SZ * 4;                          // 12.8 MB
    unsigned short* ifus_bf = (unsigned short*)p; p += ITM_SZ * 2;     //  6.4 MB
    int* e_starts = (int*)p; p += (N_ENTITIES + 1) * 4;
    int* c_starts = (int*)p; p += (N_ITEMS + 1) * 4;
    int* r_starts = (int*)p; p += (N_USERS + 1) * 4;
    unsigned short* rank_e = (unsigned short*)p; p += (size_t)N_EDGES * 2; // 4 MB
    unsigned short* rank_c = (unsigned short*)p; p += (size_t)N_INTER * 2; // 2 MB
    unsigned short* rank_r = (unsigned short*)p; p += (size_t)N_INTER * 2; // 2 MB
    p = (char*)(((size_t)p + 15) & ~(size_t)15);
    int* e_sorted = (int*)p; p += (size_t)N_EDGES * 4;                 //  8 MB
    int* i_srow   = (int*)p; p += (size_t)N_INTER * 4;                 //  4 MB
    int* i_scol   = (int*)p; p += (size_t)N_INTER * 4;                 //  4 MB
    int* packed   = (int*)p; p += (size_t)N_EDGES * 4;                 //  8 MB
    int* blk_sums = (int*)p; p += NBLK_TOT * 4;
    int* blk_off  = (int*)p; p += NBLK_TOT * 4;
    // partial[NS][KTOT] = 25.6 MB aliases agg+iint (exactly 25.6 MB): CSR
    // build completes before agg/iint are first written in the hop loop.
    int* partial = (int*)agg;

    // bf16 conversion + payload packing (one streaming kernel)
    prep_k<<<2048, 256, 0, stream>>>((const float4*)entity_emb, (ushort4*)ent0_bf,
                                     (int)(ENT_SZ / 4),
                                     (const float4*)user_emb, (ushort4*)usr0_bf,
                                     (int)(USR_SZ / 4),
                                     edge_tail, edge_type, packed);

    // CSR build: ZERO global atomics end-to-end (ranks from hist's LDS
    // atomicAdd return; scatter is pure stores at full occupancy)
    hist_part_k<<<NR_TOT * NS, 256, 0, stream>>>(edge_head, mat_col, mat_row,
                                                 partial, rank_e, rank_c, rank_r);
    scanA_k<<<NBLK_TOT, 256, 0, stream>>>(partial, blk_sums);
    scanB_k<<<1, 512, 0, stream>>>(blk_sums, blk_off, e_starts, c_starts, r_starts);
    scanC_k<<<NBLK_TOT, 256, 0, stream>>>(partial, blk_off,
                                          e_starts, c_starts, r_starts);
    scatter_e_k<<<4096, 256, 0, stream>>>(edge_head, packed, rank_e, partial,
                                          e_sorted);
    scatter_i_k<<<4096, 256, 0, stream>>>(mat_col, mat_row, rank_c, rank_r,
                                          partial, i_srow, i_scol);

    for (int hop = 0; hop < 2; ++hop) {
        const unsigned short* ent_src = (hop == 0) ? ent0_bf : ent_cur_bf;
        const unsigned short* usr_src = (hop == 0) ? usr0_bf : usr_cur_bf;
        int first = (hop == 0);
        agg_all_k<<<EB + IB, 256, 0, stream>>>((const ushort4*)ent_src, entity_emb,
                                               wrel, e_starts, e_sorted,
                                               agg, (ushort4*)ent_cur_bf, ent_res,
                                               (const ushort4*)usr_src, c_starts,
                                               i_srow, iint, first);
        fuse_k<<<NTILE, 256, 0, stream>>>(agg, iint, g1, g2, entity_emb,
                                          ifus_bf, ent_cur_bf,
                                          ent_res, kg_res, int_res, first);
        user_agg_k<<<2048, 256, 0, stream>>>((const ushort4*)ifus_bf, r_starts,
                                             i_scol, user_emb,
                                             (ushort4*)usr_cur_bf, usr_res, first);
    }
}

// Round 18
// 533.745 us; speedup vs baseline: 1.1357x; 1.1357x over previous
//
#include <hip/hip_runtime.h>
#include <math.h>

#define N_USERS    200000
#define N_ITEMS    50000
#define N_ENTITIES 150000
#define N_EDGES    2000000
#define N_INTER    1000000
#define D          64

// scan decomposition: chunks of 1250 keys over concatenated key space e|c|r
#define CHUNK      1250
#define THR_OWN    5        // 250 active threads * 5 = 1250
#define NBLK_E     120      // 150000 / 1250
#define NBLK_C     40       //  50000 / 1250
#define NBLK_R     160      // 200000 / 1250
#define NBLK_TOT   (NBLK_E + NBLK_C + NBLK_R)   // 320

// LDS-binned histogram: key ranges x slices (NO global atomics).
// RK=16384 (64 KB LDS), 1024-thread blocks: 16 waves/block x 2 blocks/CU
// = 32 waves/CU (full occupancy); r17's RK=8192 doubled read volume.
#define RK     16384        // keys per range (64 KB LDS)
#define NS     16           // slices per index array
#define NR_E   10           // ceil(150000/16384)
#define NR_C   4            // ceil( 50000/16384)
#define NR_R   13           // ceil(200000/16384)
#define NR_TOT (NR_E + NR_C + NR_R)             // 27
#define KTOT   (N_ENTITIES + N_ITEMS + N_USERS) // 400000
#define HT     1024         // hist block size

// merged agg kernel block split
#define EB     2048         // blocks for edge role
#define IB     1024         // blocks for inter role

// fuse GEMM tiling
#define FT    64            // items per tile
#define FPAD  132           // LDS row stride in floats (128 + 4)
#define NTILE ((N_ITEMS + FT - 1) / FT)   // 782

// ---- bf16 helpers (tables are bf16; all accumulation stays fp32) ----
__device__ __forceinline__ unsigned short f2bf(float f) {
    unsigned u = __float_as_uint(f);
    u += 0x7FFFu + ((u >> 16) & 1u);       // round-to-nearest-even
    return (unsigned short)(u >> 16);
}
__device__ __forceinline__ ushort4 f2bf4(float4 f) {
    ushort4 o;
    o.x = f2bf(f.x); o.y = f2bf(f.y); o.z = f2bf(f.z); o.w = f2bf(f.w);
    return o;
}
__device__ __forceinline__ float4 bf2f4(ushort4 h) {
    float4 f;
    f.x = __uint_as_float(((unsigned)h.x) << 16);
    f.y = __uint_as_float(((unsigned)h.y) << 16);
    f.z = __uint_as_float(((unsigned)h.z) << 16);
    f.w = __uint_as_float(((unsigned)h.w) << 16);
    return f;
}

// sum across the 16 lanes of a quarter (offsets 1..8 stay inside quarter)
__device__ __forceinline__ float qsum16(float v) {
#pragma unroll
    for (int off = 1; off < 16; off <<= 1) v += __shfl_xor(v, off, 64);
    return v;
}

// ---- cvt fp32->bf16 tables + pack tail|type<<18 (one streaming kernel) ----
__global__ void prep_k(const float4* __restrict__ a, ushort4* __restrict__ ab, int na4,
                       const float4* __restrict__ b, ushort4* __restrict__ bb, int nb4,
                       const int* __restrict__ tail, const int* __restrict__ type,
                       int* __restrict__ packed) {
    int n = na4 + nb4 + N_EDGES;
    for (int i = blockIdx.x * blockDim.x + threadIdx.x; i < n;
         i += gridDim.x * blockDim.x) {
        if (i < na4) ab[i] = f2bf4(a[i]);
        else if (i < na4 + nb4) bb[i - na4] = f2bf4(b[i - na4]);
        else {
            int j = i - na4 - nb4;
            packed[j] = tail[j] | (type[j] << 18);
        }
    }
}

// resolve range -> (source array geometry) for hist
__device__ __forceinline__ void range_geom(int r, const int*& src, int& n,
                                           int& base, int& cbase, int& rlen,
                                           const int* head, const int* mcol,
                                           const int* mrow) {
    if (r < NR_E) {
        src = head; n = N_EDGES; base = r * RK; cbase = 0;
        rlen = N_ENTITIES - base;
    } else if (r < NR_E + NR_C) {
        src = mcol; n = N_INTER; base = (r - NR_E) * RK;
        cbase = N_ENTITIES; rlen = N_ITEMS - base;
    } else {
        src = mrow; n = N_INTER; base = (r - NR_E - NR_C) * RK;
        cbase = N_ENTITIES + N_ITEMS; rlen = N_USERS - base;
    }
    if (rlen > RK) rlen = RK;
}

// ---- hist: per-(range,slice) LDS histogram -> partial[s][key], AND record
// each element's rank within its (slice,key) cell (the LDS atomicAdd return
// value, free). Ranks make the later scatter 100% atomic-free. 1024-thread
// blocks: 16 waves x 2 blocks/CU (64KB LDS) = full occupancy. ----
__global__ void hist_part_k(const int* __restrict__ head,
                            const int* __restrict__ mcol,
                            const int* __restrict__ mrow,
                            int* __restrict__ partial,
                            unsigned short* __restrict__ rank_e,
                            unsigned short* __restrict__ rank_c,
                            unsigned short* __restrict__ rank_r) {
    __shared__ int lh[RK];
    int r = blockIdx.x >> 4, s = blockIdx.x & (NS - 1);
    for (int d = threadIdx.x; d < RK; d += HT) lh[d] = 0;
    __syncthreads();
    const int* src; int n, base, cbase, rlen;
    range_geom(r, src, n, base, cbase, rlen, head, mcol, mrow);
    unsigned short* rank = (r < NR_E) ? rank_e
                         : (r < NR_E + NR_C) ? rank_c : rank_r;
    int chunk = n / NS;
    int lo = s * chunk, hi = lo + chunk;
    int i = lo + threadIdx.x;
    for (; i + 3 * HT < hi; i += 4 * HT) {   // 4-way MLP on L3-resident reads
        unsigned d0 = (unsigned)(__builtin_nontemporal_load(&src[i])          - base);
        unsigned d1 = (unsigned)(__builtin_nontemporal_load(&src[i + HT])     - base);
        unsigned d2 = (unsigned)(__builtin_nontemporal_load(&src[i + 2 * HT]) - base);
        unsigned d3 = (unsigned)(__builtin_nontemporal_load(&src[i + 3 * HT]) - base);
        if (d0 < (unsigned)RK) rank[i]          = (unsigned short)atomicAdd(&lh[d0], 1);
        if (d1 < (unsigned)RK) rank[i + HT]     = (unsigned short)atomicAdd(&lh[d1], 1);
        if (d2 < (unsigned)RK) rank[i + 2 * HT] = (unsigned short)atomicAdd(&lh[d2], 1);
        if (d3 < (unsigned)RK) rank[i + 3 * HT] = (unsigned short)atomicAdd(&lh[d3], 1);
    }
    for (; i < hi; i += HT) {
        unsigned d = (unsigned)(__builtin_nontemporal_load(&src[i]) - base);
        if (d < (unsigned)RK) rank[i] = (unsigned short)atomicAdd(&lh[d], 1);
    }
    __syncthreads();
    int* dst = partial + (size_t)s * KTOT + cbase + base;
    for (int d = threadIdx.x; d < rlen; d += HT) dst[d] = lh[d];
}

// ---- scan stage A: per-chunk sums of key totals (sum over slices) ----
__global__ void scanA_k(const int* __restrict__ partial,
                        int* __restrict__ blk_sums) {
    __shared__ int ss[256];
    int b = blockIdx.x, t = threadIdx.x;
    int base = b * CHUNK;
    int sum = 0;
    if (t < 250) {
        int g = base + t * THR_OWN;
#pragma unroll
        for (int s = 0; s < NS; ++s) {
            const int* p = partial + (size_t)s * KTOT + g;
#pragma unroll
            for (int j = 0; j < THR_OWN; ++j) sum += p[j];
        }
    }
    ss[t] = sum;
    __syncthreads();
    for (int off = 128; off > 0; off >>= 1) {
        if (t < off) ss[t] += ss[t + off];
        __syncthreads();
    }
    if (t == 0) blk_sums[b] = ss[0];
}

// ---- scan stage B: single block scans 320 partials, segment-reset ----
__global__ void scanB_k(int* __restrict__ blk_sums, int* __restrict__ blk_off,
                        int* __restrict__ e_starts, int* __restrict__ c_starts,
                        int* __restrict__ r_starts) {
    __shared__ int ss[512];
    int t = threadIdx.x;
    ss[t] = (t < NBLK_TOT) ? blk_sums[t] : 0;
    __syncthreads();
    for (int off = 1; off < 512; off <<= 1) {
        int v = (t >= off) ? ss[t - off] : 0;
        __syncthreads();
        ss[t] += v;   // inclusive scan
        __syncthreads();
    }
    if (t < NBLK_TOT) {
        int excl = (t == 0) ? 0 : ss[t - 1];
        int segstart_excl;
        if (t < NBLK_E) segstart_excl = 0;
        else if (t < NBLK_E + NBLK_C) segstart_excl = ss[NBLK_E - 1];
        else segstart_excl = ss[NBLK_E + NBLK_C - 1];
        blk_off[t] = excl - segstart_excl;
    }
    if (t == 0) {
        e_starts[N_ENTITIES] = N_EDGES;
        c_starts[N_ITEMS]    = N_INTER;
        r_starts[N_USERS]    = N_INTER;
    }
}

// ---- scan stage C: write starts[key]; transform partial[s][key] in place
// into the (slice,key) cursor start = starts[key] + sum_{s'<s} partial ----
__global__ void scanC_k(int* __restrict__ partial,
                        const int* __restrict__ blk_off,
                        int* __restrict__ e_starts, int* __restrict__ c_starts,
                        int* __restrict__ r_starts) {
    __shared__ int ss[256];
    int b = blockIdx.x, t = threadIdx.x;
    int base = b * CHUNK;
    int tot[THR_OWN];
    int sum = 0;
    if (t < 250) {
        int g = base + t * THR_OWN;
#pragma unroll
        for (int j = 0; j < THR_OWN; ++j) tot[j] = 0;
#pragma unroll
        for (int s = 0; s < NS; ++s) {
            const int* p = partial + (size_t)s * KTOT + g;
#pragma unroll
            for (int j = 0; j < THR_OWN; ++j) tot[j] += p[j];
        }
#pragma unroll
        for (int j = 0; j < THR_OWN; ++j) sum += tot[j];
    }
    ss[t] = sum;
    __syncthreads();
    for (int off = 1; off < 256; off <<= 1) {
        int v = (t >= off) ? ss[t - off] : 0;
        __syncthreads();
        ss[t] += v;
        __syncthreads();
    }
    if (t < 250) {
        int run = blk_off[b] + ((t == 0) ? 0 : ss[t - 1]);
        int* sarr; int ebase;
        if (b < NBLK_E)               { sarr = e_starts; ebase = base; }
        else if (b < NBLK_E + NBLK_C) { sarr = c_starts; ebase = base - NBLK_E * CHUNK; }
        else                          { sarr = r_starts; ebase = base - (NBLK_E + NBLK_C) * CHUNK; }
        int gl = ebase + t * THR_OWN;
        int gg = base + t * THR_OWN;
        for (int j = 0; j < THR_OWN; ++j) {
            sarr[gl + j] = run;
            int cur = run;
#pragma unroll
            for (int s = 0; s < NS; ++s) {
                int idx = s * KTOT + gg + j;
                int v = partial[idx];
                partial[idx] = cur;
                cur += v;
            }
            run = cur;
        }
    }
}

// ---- scatter: ZERO atomics. pos = cursor[s][key] + rank[i]. XCD key-range
// partitioned (proven r13 store-locality form), full occupancy. ----
__global__ void scatter_e_k(const int* __restrict__ head,
                            const int* __restrict__ packed,
                            const unsigned short* __restrict__ rank_e,
                            const int* __restrict__ partial,
                            int* __restrict__ e_sorted) {
    int xcd = blockIdx.x & 7;
    int slot = blockIdx.x >> 3;
    int nslot = gridDim.x >> 3;
    int lo = xcd * (N_ENTITIES / 8);
    int hi = lo + (N_ENTITIES / 8);
    for (int i = slot * blockDim.x + threadIdx.x; i < N_EDGES;
         i += nslot * blockDim.x) {
        int h = __builtin_nontemporal_load(&head[i]);
        if (h >= lo && h < hi) {
            int s = i / (N_EDGES / NS);
            int pos = partial[(size_t)s * KTOT + h]
                    + (int)__builtin_nontemporal_load(&rank_e[i]);
            e_sorted[pos] = __builtin_nontemporal_load(&packed[i]);
        }
    }
}

__global__ void scatter_i_k(const int* __restrict__ mcol,
                            const int* __restrict__ mrow,
                            const unsigned short* __restrict__ rank_c,
                            const unsigned short* __restrict__ rank_r,
                            const int* __restrict__ partial,
                            int* __restrict__ i_srow, int* __restrict__ i_scol) {
    int xcd = blockIdx.x & 7;
    int slot = blockIdx.x >> 3;
    int nslot = gridDim.x >> 3;
    int clo = xcd * (N_ITEMS / 8), chi = clo + (N_ITEMS / 8);
    int rlo = xcd * (N_USERS / 8), rhi = rlo + (N_USERS / 8);
    for (int i = slot * blockDim.x + threadIdx.x; i < N_INTER;
         i += nslot * blockDim.x) {
        int c = __builtin_nontemporal_load(&mcol[i]);
        int r = __builtin_nontemporal_load(&mrow[i]);
        int s = i / (N_INTER / NS);
        if (c >= clo && c < chi) {
            int pos = partial[(size_t)s * KTOT + N_ENTITIES + c]
                    + (int)__builtin_nontemporal_load(&rank_c[i]);
            i_srow[pos] = r;
        }
        if (r >= rlo && r < rhi) {
            int pos = partial[(size_t)s * KTOT + N_ENTITIES + N_ITEMS + r]
                    + (int)__builtin_nontemporal_load(&rank_r[i]);
            i_scol[pos] = c;
        }
    }
}

// ---- merged aggregation, QUARTER-PER-ROW: each 16-lane quarter owns one
// row entirely (16 lanes x ushort4 = full 128B bf16 row). Per-quarter loop
// divergence is safe: every __shfl source (lane&48)|k stays inside the
// quarter's own (active) lanes. ----
__global__ void agg_all_k(const ushort4* __restrict__ ent_bf,
                          const float* __restrict__ ent0f,
                          const float* __restrict__ wrel,
                          const int* __restrict__ es,
                          const int* __restrict__ e_sorted,
                          float* __restrict__ agg,
                          ushort4* __restrict__ ent_cur_bf,
                          float* __restrict__ ent_res,
                          const ushort4* __restrict__ usr_bf,
                          const int* __restrict__ cs,
                          const int* __restrict__ i_srow,
                          float* __restrict__ iint,
                          int first) {
    int lane = threadIdx.x & 63;
    int q = lane >> 4, ql = lane & 15;
    int qb = lane & 48;
    if (blockIdx.x < EB) {
        __shared__ float4 wl4[32 * 16];   // 32 relations x 16 float4 (fp32)
        for (int idx = threadIdx.x; idx < 512; idx += 256)
            wl4[idx] = ((const float4*)wrel)[idx];
        __syncthreads();
        int qid = (blockIdx.x * 4 + (threadIdx.x >> 6)) * 4 + q;
        int nq = EB * 16;
        for (int h = qid; h < N_ENTITIES; h += nq) {
            int beg = es[h], end = es[h + 1];
            float4 a0 = {0, 0, 0, 0}, a1 = {0, 0, 0, 0};
            for (int j0 = beg; j0 < end; j0 += 16) {
                int p = (j0 + ql < end) ? e_sorted[j0 + ql] : 0;
                int mm = end - j0; if (mm > 16) mm = 16;
                int k = 0;
                for (; k + 1 < mm; k += 2) {
                    int p0 = __shfl(p, qb | k, 64);
                    int p1 = __shfl(p, qb | (k + 1), 64);
                    float4 e0 = bf2f4(ent_bf[(size_t)(p0 & 0x3FFFF) * 16 + ql]);
                    float4 w0 = wl4[((p0 >> 18) << 4) + ql];
                    float4 e1 = bf2f4(ent_bf[(size_t)(p1 & 0x3FFFF) * 16 + ql]);
                    float4 w1 = wl4[((p1 >> 18) << 4) + ql];
                    a0.x = fmaf(e0.x, w0.x, a0.x); a0.y = fmaf(e0.y, w0.y, a0.y);
                    a0.z = fmaf(e0.z, w0.z, a0.z); a0.w = fmaf(e0.w, w0.w, a0.w);
                    a1.x = fmaf(e1.x, w1.x, a1.x); a1.y = fmaf(e1.y, w1.y, a1.y);
                    a1.z = fmaf(e1.z, w1.z, a1.z); a1.w = fmaf(e1.w, w1.w, a1.w);
                }
                if (k < mm) {
                    int p0 = __shfl(p, qb | k, 64);
                    float4 e0 = bf2f4(ent_bf[(size_t)(p0 & 0x3FFFF) * 16 + ql]);
                    float4 w0 = wl4[((p0 >> 18) << 4) + ql];
                    a0.x = fmaf(e0.x, w0.x, a0.x); a0.y = fmaf(e0.y, w0.y, a0.y);
                    a0.z = fmaf(e0.z, w0.z, a0.z); a0.w = fmaf(e0.w, w0.w, a0.w);
                }
            }
            float4 v; v.x = a0.x + a1.x; v.y = a0.y + a1.y;
            v.z = a0.z + a1.z; v.w = a0.w + a1.w;
            if (h < N_ITEMS) {
                int d = end - beg;
                float inv = 1.0f / (float)(d > 0 ? d : 1);
                float4 o; o.x = v.x * inv; o.y = v.y * inv;
                o.z = v.z * inv; o.w = v.w * inv;
                ((float4*)agg)[(size_t)h * 16 + ql] = o;
            } else {
                // l2norm(mean) == l2norm(sum): scale-invariant
                float s = qsum16(fmaf(v.x, v.x, fmaf(v.y, v.y, fmaf(v.z, v.z, v.w * v.w))));
                float inv = 1.0f / fmaxf(sqrtf(s), 1e-12f);
                float4 vn; vn.x = v.x * inv; vn.y = v.y * inv;
                vn.z = v.z * inv; vn.w = v.w * inv;
                size_t o4 = (size_t)h * 16 + ql;
                if (first) {
                    ent_cur_bf[o4] = f2bf4(vn);
                    float4 b = ((const float4*)ent0f)[o4];
                    b.x += vn.x; b.y += vn.y; b.z += vn.z; b.w += vn.w;
                    ((float4*)ent_res)[o4] = b;
                } else {
                    float4 r = ((float4*)ent_res)[o4];
                    r.x += vn.x; r.y += vn.y; r.z += vn.z; r.w += vn.w;
                    ((float4*)ent_res)[o4] = r;
                }
            }
        }
    } else {
        int qid = ((blockIdx.x - EB) * 4 + (threadIdx.x >> 6)) * 4 + q;
        int nq = IB * 16;
        for (int c = qid; c < N_ITEMS; c += nq) {
            int beg = cs[c], end = cs[c + 1];
            float4 a0 = {0, 0, 0, 0}, a1 = {0, 0, 0, 0};
            for (int j0 = beg; j0 < end; j0 += 16) {
                int p = (j0 + ql < end) ? i_srow[j0 + ql] : 0;
                int mm = end - j0; if (mm > 16) mm = 16;
                int k = 0;
                for (; k + 1 < mm; k += 2) {
                    int p0 = __shfl(p, qb | k, 64);
                    int p1 = __shfl(p, qb | (k + 1), 64);
                    float4 u0 = bf2f4(usr_bf[(size_t)p0 * 16 + ql]);
                    float4 u1 = bf2f4(usr_bf[(size_t)p1 * 16 + ql]);
                    a0.x += u0.x; a0.y += u0.y; a0.z += u0.z; a0.w += u0.w;
                    a1.x += u1.x; a1.y += u1.y; a1.z += u1.z; a1.w += u1.w;
                }
                if (k < mm) {
                    int p0 = __shfl(p, qb | k, 64);
                    float4 u0 = bf2f4(usr_bf[(size_t)p0 * 16 + ql]);
                    a0.x += u0.x; a0.y += u0.y; a0.z += u0.z; a0.w += u0.w;
                }
            }
            float4 v; v.x = a0.x + a1.x; v.y = a0.y + a1.y;
            v.z = a0.z + a1.z; v.w = a0.w + a1.w;
            int d = end - beg;
            float inv = 1.0f / (float)(d > 0 ? d : 1);
            float4 o; o.x = v.x * inv; o.y = v.y * inv;
            o.z = v.z * inv; o.w = v.w * inv;
            ((float4*)iint)[(size_t)c * 16 + ql] = o;
        }
    }
}

// ---- fuse: register-tiled LDS GEMM, y = [kg|ii] @ [g1|g2]^T ----
// outputs: ifus_bf + ent_cur_bf (bf16 gather tables), fp32 residuals.
__global__ void fuse_k(const float* __restrict__ agg,
                       const float* __restrict__ iint,
                       const float* __restrict__ g1,
                       const float* __restrict__ g2,
                       const float* __restrict__ ent0,
                       unsigned short* __restrict__ ifus_bf,
                       unsigned short* __restrict__ ent_cur_bf,
                       float* __restrict__ ent_res,
                       float* __restrict__ kg_res,
                       float* __restrict__ int_res,
                       int first) {
    __shared__ float A[FT * FPAD];   // [item][k]: k 0..63 = kg, 64..127 = ii
    __shared__ float B[64 * FPAD];   // [j][k]:    k 0..63 = g1, 64..127 = g2
    int t = threadIdx.x;
    int ibase = blockIdx.x * FT;

    {
        const float4* g14 = (const float4*)g1;
        const float4* g24 = (const float4*)g2;
        const float4* a4 = (const float4*)(agg + (size_t)ibase * D);
        const float4* i4 = (const float4*)(iint + (size_t)ibase * D);
        for (int idx = t; idx < 1024; idx += 256) {
            int r = idx >> 4, kq = idx & 15;
            ((float4*)&B[r * FPAD])[kq]      = g14[idx];
            ((float4*)&B[r * FPAD + 64])[kq] = g24[idx];
            ((float4*)&A[r * FPAD])[kq]      = a4[idx];   // benign OOB read on
            ((float4*)&A[r * FPAD + 64])[kq] = i4[idx];   // tail tile (ws mem)
        }
    }
    __syncthreads();

    int ti = t >> 4, tj = t & 15;

    float y[4][4] = {};
    for (int k = 0; k < 128; k += 4) {
        float4 av[4], bv[4];
#pragma unroll
        for (int a = 0; a < 4; ++a) av[a] = *(const float4*)&A[(ti + 16 * a) * FPAD + k];
#pragma unroll
        for (int b = 0; b < 4; ++b) bv[b] = *(const float4*)&B[(tj + 16 * b) * FPAD + k];
#pragma unroll
        for (int a = 0; a < 4; ++a)
#pragma unroll
            for (int b = 0; b < 4; ++b) {
                y[a][b] = fmaf(av[a].x, bv[b].x, y[a][b]);
                y[a][b] = fmaf(av[a].y, bv[b].y, y[a][b]);
                y[a][b] = fmaf(av[a].z, bv[b].z, y[a][b]);
                y[a][b] = fmaf(av[a].w, bv[b].w, y[a][b]);
            }
    }

    float fus[4][4], kg[4][4], ii[4][4];
    float sf[4], sk[4], si[4];
#pragma unroll
    for (int a = 0; a < 4; ++a) { sf[a] = 0.f; sk[a] = 0.f; si[a] = 0.f; }
#pragma unroll
    for (int a = 0; a < 4; ++a) {
        int i = ti + 16 * a;
#pragma unroll
        for (int b = 0; b < 4; ++b) {
            int j = tj + 16 * b;
            float K = A[i * FPAD + j];
            float I = A[i * FPAD + 64 + j];
            float gi = 1.0f / (1.0f + __expf(-y[a][b]));
            float f = gi * K + (1.0f - gi) * I;
            fus[a][b] = f; kg[a][b] = K; ii[a][b] = I;
            sf[a] = fmaf(f, f, sf[a]);
            sk[a] = fmaf(K, K, sk[a]);
            si[a] = fmaf(I, I, si[a]);
        }
    }
#pragma unroll
    for (int off = 1; off < 16; off <<= 1) {
#pragma unroll
        for (int a = 0; a < 4; ++a) {
            sf[a] += __shfl_xor(sf[a], off, 64);
            sk[a] += __shfl_xor(sk[a], off, 64);
            si[a] += __shfl_xor(si[a], off, 64);
        }
    }

#pragma unroll
    for (int a = 0; a < 4; ++a) {
        int i = ibase + ti + 16 * a;
        if (i < N_ITEMS) {
            float nf = 1.0f / fmaxf(sqrtf(sf[a]), 1e-12f);
            float nk = 1.0f / fmaxf(sqrtf(sk[a]), 1e-12f);
            float ni = 1.0f / fmaxf(sqrtf(si[a]), 1e-12f);
#pragma unroll
            for (int b = 0; b < 4; ++b) {
                size_t o = (size_t)i * D + tj + 16 * b;
                float f = fus[a][b];
                ifus_bf[o] = f2bf(f);
                float fn = f * nf;
                ent_cur_bf[o] = f2bf(fn);
                if (first) {
                    ent_res[o] = ent0[o] + fn;
                    kg_res[o]  = kg[a][b] * nk;
                    int_res[o] = ii[a][b] * ni;
                } else {
                    ent_res[o] += fn;
                    kg_res[o]  += kg[a][b] * nk;
                    int_res[o] += ii[a][b] * ni;
                }
            }
        }
    }
}

// ---- per-user segment sum of item_fusion + l2 norm (quarter-per-row) ----
__global__ void user_agg_k(const ushort4* __restrict__ ifus_bf,
                           const int* __restrict__ rs,
                           const int* __restrict__ i_scol,
                           const float* __restrict__ usr0,
                           ushort4* __restrict__ usr_cur_bf,
                           float* __restrict__ usr_res,
                           int first) {
    const float4* u04 = (const float4*)usr0;
    int lane = threadIdx.x & 63;
    int q = lane >> 4, ql = lane & 15;
    int qb = lane & 48;
    int qid = (blockIdx.x * (blockDim.x >> 6) + (threadIdx.x >> 6)) * 4 + q;
    int nq = gridDim.x * (blockDim.x >> 6) * 4;
    for (int u = qid; u < N_USERS; u += nq) {
        int beg = rs[u], end = rs[u + 1];
        float4 a0 = {0, 0, 0, 0}, a1 = {0, 0, 0, 0};
        for (int j0 = beg; j0 < end; j0 += 16) {
            int p = (j0 + ql < end) ? i_scol[j0 + ql] : 0;
            int mm = end - j0; if (mm > 16) mm = 16;
            int k = 0;
            for (; k + 1 < mm; k += 2) {
                int p0 = __shfl(p, qb | k, 64);
                int p1 = __shfl(p, qb | (k + 1), 64);
                float4 u0 = bf2f4(ifus_bf[(size_t)p0 * 16 + ql]);
                float4 u1 = bf2f4(ifus_bf[(size_t)p1 * 16 + ql]);
                a0.x += u0.x; a0.y += u0.y; a0.z += u0.z; a0.w += u0.w;
                a1.x += u1.x; a1.y += u1.y; a1.z += u1.z; a1.w += u1.w;
            }
            if (k < mm) {
                int p0 = __shfl(p, qb | k, 64);
                float4 u0 = bf2f4(ifus_bf[(size_t)p0 * 16 + ql]);
                a0.x += u0.x; a0.y += u0.y; a0.z += u0.z; a0.w += u0.w;
            }
        }
        float4 v; v.x = a0.x + a1.x; v.y = a0.y + a1.y;
        v.z = a0.z + a1.z; v.w = a0.w + a1.w;
        float s = qsum16(fmaf(v.x, v.x, fmaf(v.y, v.y, fmaf(v.z, v.z, v.w * v.w))));
        float inv = 1.0f / fmaxf(sqrtf(s), 1e-12f);
        float4 vn; vn.x = v.x * inv; vn.y = v.y * inv;
        vn.z = v.z * inv; vn.w = v.w * inv;
        size_t o4 = (size_t)u * 16 + ql;
        usr_cur_bf[o4] = f2bf4(vn);
        if (first) {
            float4 b = u04[o4];
            b.x += vn.x; b.y += vn.y; b.z += vn.z; b.w += vn.w;
            ((float4*)usr_res)[o4] = b;
        } else {
            float4 r = ((float4*)usr_res)[o4];
            r.x += vn.x; r.y += vn.y; r.z += vn.z; r.w += vn.w;
            ((float4*)usr_res)[o4] = r;
        }
    }
}

extern "C" void kernel_launch(void* const* d_in, const int* in_sizes, int n_in,
                              void* d_out, int out_size, void* d_ws, size_t ws_size,
                              hipStream_t stream) {
    const float* user_emb   = (const float*)d_in[0];
    const float* entity_emb = (const float*)d_in[1];
    const float* wrel       = (const float*)d_in[2];
    const float* g1         = (const float*)d_in[3];
    const float* g2         = (const float*)d_in[4];
    const int*   edge_head  = (const int*)d_in[5];
    const int*   edge_tail  = (const int*)d_in[6];
    const int*   edge_type  = (const int*)d_in[7];
    const int*   mat_row    = (const int*)d_in[8];
    const int*   mat_col    = (const int*)d_in[9];

    const size_t ENT_SZ = (size_t)N_ENTITIES * D;  //  9.6M
    const size_t USR_SZ = (size_t)N_USERS * D;     // 12.8M
    const size_t ITM_SZ = (size_t)N_ITEMS * D;     //  3.2M

    float* out     = (float*)d_out;
    float* ent_res = out;
    float* usr_res = out + ENT_SZ;
    float* kg_res  = out + ENT_SZ + USR_SZ;
    float* int_res = out + ENT_SZ + USR_SZ + ITM_SZ;

    // workspace layout (bf16 gather tables + fp32 staging)
    char* p = (char*)d_ws;
    unsigned short* ent_cur_bf = (unsigned short*)p; p += ENT_SZ * 2;  // 19.2 MB
    unsigned short* usr_cur_bf = (unsigned short*)p; p += USR_SZ * 2;  // 25.6 MB
    unsigned short* ent0_bf    = (unsigned short*)p; p += ENT_SZ * 2;  // 19.2 MB
    unsigned short* usr0_bf    = (unsigned short*)p; p += USR_SZ * 2;  // 25.6 MB
    float* agg  = (float*)p; p += ITM_SZ * 4;                          // 12.8 MB
    float* iint = (float*)p; p += ITM_SZ * 4;                          // 12.8 MB
    unsigned short* ifus_bf = (unsigned short*)p; p += ITM_SZ * 2;     //  6.4 MB
    int* e_starts = (int*)p; p += (N_ENTITIES + 1) * 4;
    int* c_starts = (int*)p; p += (N_ITEMS + 1) * 4;
    int* r_starts = (int*)p; p += (N_USERS + 1) * 4;
    unsigned short* rank_e = (unsigned short*)p; p += (size_t)N_EDGES * 2; // 4 MB
    unsigned short* rank_c = (unsigned short*)p; p += (size_t)N_INTER * 2; // 2 MB
    unsigned short* rank_r = (unsigned short*)p; p += (size_t)N_INTER * 2; // 2 MB
    p = (char*)(((size_t)p + 15) & ~(size_t)15);
    int* e_sorted = (int*)p; p += (size_t)N_EDGES * 4;                 //  8 MB
    int* i_srow   = (int*)p; p += (size_t)N_INTER * 4;                 //  4 MB
    int* i_scol   = (int*)p; p += (size_t)N_INTER * 4;                 //  4 MB
    int* packed   = (int*)p; p += (size_t)N_EDGES * 4;                 //  8 MB
    int* blk_sums = (int*)p; p += NBLK_TOT * 4;
    int* blk_off  = (int*)p; p += NBLK_TOT * 4;
    // partial[NS][KTOT] = 25.6 MB aliases agg+iint (exactly 25.6 MB): CSR
    // build completes before agg/iint are first written in the hop loop.
    int* partial = (int*)agg;

    // bf16 conversion + payload packing (one streaming kernel)
    prep_k<<<2048, 256, 0, stream>>>((const float4*)entity_emb, (ushort4*)ent0_bf,
                                     (int)(ENT_SZ / 4),
                                     (const float4*)user_emb, (ushort4*)usr0_bf,
                                     (int)(USR_SZ / 4),
                                     edge_tail, edge_type, packed);

    // CSR build: ZERO global atomics end-to-end (ranks from hist's LDS
    // atomicAdd return; scatter is pure stores at full occupancy)
    hist_part_k<<<NR_TOT * NS, HT, 0, stream>>>(edge_head, mat_col, mat_row,
                                                partial, rank_e, rank_c, rank_r);
    scanA_k<<<NBLK_TOT, 256, 0, stream>>>(partial, blk_sums);
    scanB_k<<<1, 512, 0, stream>>>(blk_sums, blk_off, e_starts, c_starts, r_starts);
    scanC_k<<<NBLK_TOT, 256, 0, stream>>>(partial, blk_off,
                                          e_starts, c_starts, r_starts);
    scatter_e_k<<<4096, 256, 0, stream>>>(edge_head, packed, rank_e, partial,
                                          e_sorted);
    scatter_i_k<<<4096, 256, 0, stream>>>(mat_col, mat_row, rank_c, rank_r,
                                          partial, i_srow, i_scol);

    for (int hop = 0; hop < 2; ++hop) {
        const unsigned short* ent_src = (hop == 0) ? ent0_bf : ent_cur_bf;
        const unsigned short* usr_src = (hop == 0) ? usr0_bf : usr_cur_bf;
        int first = (hop == 0);
        agg_all_k<<<EB + IB, 256, 0, stream>>>((const ushort4*)ent_src, entity_emb,
                                               wrel, e_starts, e_sorted,
                                               agg, (ushort4*)ent_cur_bf, ent_res,
                                               (const ushort4*)usr_src, c_starts,
                                               i_srow, iint, first);
        fuse_k<<<NTILE, 256, 0, stream>>>(agg, iint, g1, g2, entity_emb,
                                          ifus_bf, ent_cur_bf,
                                          ent_res, kg_res, int_res, first);
        user_agg_k<<<2048, 256, 0, stream>>>((const ushort4*)ifus_bf, r_starts,
                                             i_scol, user_emb,
                                             (ushort4*)usr_cur_bf, usr_res, first);
    }
}

// Round 19
// 519.550 us; speedup vs baseline: 1.1667x; 1.0273x over previous
//
#include <hip/hip_runtime.h>
#include <math.h>

#define N_USERS    200000
#define N_ITEMS    50000
#define N_ENTITIES 150000
#define N_EDGES    2000000
#define N_INTER    1000000
#define D          64

// scan decomposition: chunks of 1250 keys over concatenated key space e|c|r
#define CHUNK      1250
#define THR_OWN    5        // 250 active threads * 5 = 1250
#define NBLK_E     120      // 150000 / 1250
#define NBLK_C     40       //  50000 / 1250
#define NBLK_R     160      // 200000 / 1250
#define NBLK_TOT   (NBLK_E + NBLK_C + NBLK_R)   // 320

// LDS-binned histogram: key ranges x slices (NO global atomics).
// RK=16384 (64 KB LDS), 1024-thread blocks: 16 waves/block x 2 blocks/CU
// = 32 waves/CU (full occupancy).
#define RK     16384        // keys per range (64 KB LDS)
#define NS     16           // slices per index array
#define NR_E   10           // ceil(150000/16384)
#define NR_C   4            // ceil( 50000/16384)
#define NR_R   13           // ceil(200000/16384)
#define NR_TOT (NR_E + NR_C + NR_R)             // 27
#define KTOT   (N_ENTITIES + N_ITEMS + N_USERS) // 400000
#define HT     1024         // hist block size
#define HB     (NR_TOT * NS)                    // 432 hist blocks
#define PB     1200                             // prep blocks (merged kernel)

// merged agg kernel block split
#define EB     2048         // blocks for edge role
#define IB     1024         // blocks for inter role

// merged scatter block split
#define SB     4096         // blocks per scatter role (4096 % 8 == 0)

// fuse GEMM tiling
#define FT    64            // items per tile
#define FPAD  132           // LDS row stride in floats (128 + 4)
#define NTILE ((N_ITEMS + FT - 1) / FT)   // 782

// ---- bf16 helpers (tables are bf16; all accumulation stays fp32) ----
__device__ __forceinline__ unsigned short f2bf(float f) {
    unsigned u = __float_as_uint(f);
    u += 0x7FFFu + ((u >> 16) & 1u);       // round-to-nearest-even
    return (unsigned short)(u >> 16);
}
__device__ __forceinline__ ushort4 f2bf4(float4 f) {
    ushort4 o;
    o.x = f2bf(f.x); o.y = f2bf(f.y); o.z = f2bf(f.z); o.w = f2bf(f.w);
    return o;
}
__device__ __forceinline__ float4 bf2f4(ushort4 h) {
    float4 f;
    f.x = __uint_as_float(((unsigned)h.x) << 16);
    f.y = __uint_as_float(((unsigned)h.y) << 16);
    f.z = __uint_as_float(((unsigned)h.z) << 16);
    f.w = __uint_as_float(((unsigned)h.w) << 16);
    return f;
}

// sum across the 16 lanes of a quarter (offsets 1..8 stay inside quarter)
__device__ __forceinline__ float qsum16(float v) {
#pragma unroll
    for (int off = 1; off < 16; off <<= 1) v += __shfl_xor(v, off, 64);
    return v;
}

// resolve range -> (source array geometry) for hist
__device__ __forceinline__ void range_geom(int r, const int*& src, int& n,
                                           int& base, int& cbase, int& rlen,
                                           const int* head, const int* mcol,
                                           const int* mrow) {
    if (r < NR_E) {
        src = head; n = N_EDGES; base = r * RK; cbase = 0;
        rlen = N_ENTITIES - base;
    } else if (r < NR_E + NR_C) {
        src = mcol; n = N_INTER; base = (r - NR_E) * RK;
        cbase = N_ENTITIES; rlen = N_ITEMS - base;
    } else {
        src = mrow; n = N_INTER; base = (r - NR_E - NR_C) * RK;
        cbase = N_ENTITIES + N_ITEMS; rlen = N_USERS - base;
    }
    if (rlen > RK) rlen = RK;
}

// ---- merged prep + hist: blocks [0,HB) do per-(range,slice) LDS histogram
// (recording each element's rank = LDS atomicAdd return, making the scatter
// atomic-free); blocks [HB,HB+PB) stream cvt fp32->bf16 + pack tail|type.
// The two roles are data-independent; merging overlaps prep under hist. ----
__global__ void hist_prep_k(const int* __restrict__ head,
                            const int* __restrict__ mcol,
                            const int* __restrict__ mrow,
                            int* __restrict__ partial,
                            unsigned short* __restrict__ rank_e,
                            unsigned short* __restrict__ rank_c,
                            unsigned short* __restrict__ rank_r,
                            const float4* __restrict__ enta, ushort4* __restrict__ entb,
                            int na4,
                            const float4* __restrict__ usra, ushort4* __restrict__ usrb,
                            int nb4,
                            const int* __restrict__ tail, const int* __restrict__ type,
                            int* __restrict__ packed) {
    __shared__ int lh[RK];
    if (blockIdx.x >= HB) {
        // ---- prep role: streaming cvt + pack ----
        int n = na4 + nb4 + N_EDGES;
        for (int i = (blockIdx.x - HB) * HT + threadIdx.x; i < n; i += PB * HT) {
            if (i < na4) entb[i] = f2bf4(enta[i]);
            else if (i < na4 + nb4) usrb[i - na4] = f2bf4(usra[i - na4]);
            else {
                int j = i - na4 - nb4;
                packed[j] = tail[j] | (type[j] << 18);
            }
        }
        return;
    }
    int r = blockIdx.x >> 4, s = blockIdx.x & (NS - 1);
    for (int d = threadIdx.x; d < RK; d += HT) lh[d] = 0;
    __syncthreads();
    const int* src; int n, base, cbase, rlen;
    range_geom(r, src, n, base, cbase, rlen, head, mcol, mrow);
    unsigned short* rank = (r < NR_E) ? rank_e
                         : (r < NR_E + NR_C) ? rank_c : rank_r;
    int chunk = n / NS;
    int lo = s * chunk, hi = lo + chunk;
    int i = lo + threadIdx.x;
    for (; i + 3 * HT < hi; i += 4 * HT) {   // 4-way MLP on L3-resident reads
        unsigned d0 = (unsigned)(__builtin_nontemporal_load(&src[i])          - base);
        unsigned d1 = (unsigned)(__builtin_nontemporal_load(&src[i + HT])     - base);
        unsigned d2 = (unsigned)(__builtin_nontemporal_load(&src[i + 2 * HT]) - base);
        unsigned d3 = (unsigned)(__builtin_nontemporal_load(&src[i + 3 * HT]) - base);
        if (d0 < (unsigned)RK) rank[i]          = (unsigned short)atomicAdd(&lh[d0], 1);
        if (d1 < (unsigned)RK) rank[i + HT]     = (unsigned short)atomicAdd(&lh[d1], 1);
        if (d2 < (unsigned)RK) rank[i + 2 * HT] = (unsigned short)atomicAdd(&lh[d2], 1);
        if (d3 < (unsigned)RK) rank[i + 3 * HT] = (unsigned short)atomicAdd(&lh[d3], 1);
    }
    for (; i < hi; i += HT) {
        unsigned d = (unsigned)(__builtin_nontemporal_load(&src[i]) - base);
        if (d < (unsigned)RK) rank[i] = (unsigned short)atomicAdd(&lh[d], 1);
    }
    __syncthreads();
    int* dst = partial + (size_t)s * KTOT + cbase + base;
    for (int d = threadIdx.x; d < rlen; d += HT) dst[d] = lh[d];
}

// ---- scan stage A: per-chunk sums of key totals (sum over slices) ----
__global__ void scanA_k(const int* __restrict__ partial,
                        int* __restrict__ blk_sums) {
    __shared__ int ss[256];
    int b = blockIdx.x, t = threadIdx.x;
    int base = b * CHUNK;
    int sum = 0;
    if (t < 250) {
        int g = base + t * THR_OWN;
#pragma unroll
        for (int s = 0; s < NS; ++s) {
            const int* p = partial + (size_t)s * KTOT + g;
#pragma unroll
            for (int j = 0; j < THR_OWN; ++j) sum += p[j];
        }
    }
    ss[t] = sum;
    __syncthreads();
    for (int off = 128; off > 0; off >>= 1) {
        if (t < off) ss[t] += ss[t + off];
        __syncthreads();
    }
    if (t == 0) blk_sums[b] = ss[0];
}

// ---- scan stage B: single block scans 320 partials, segment-reset ----
__global__ void scanB_k(int* __restrict__ blk_sums, int* __restrict__ blk_off,
                        int* __restrict__ e_starts, int* __restrict__ c_starts,
                        int* __restrict__ r_starts) {
    __shared__ int ss[512];
    int t = threadIdx.x;
    ss[t] = (t < NBLK_TOT) ? blk_sums[t] : 0;
    __syncthreads();
    for (int off = 1; off < 512; off <<= 1) {
        int v = (t >= off) ? ss[t - off] : 0;
        __syncthreads();
        ss[t] += v;   // inclusive scan
        __syncthreads();
    }
    if (t < NBLK_TOT) {
        int excl = (t == 0) ? 0 : ss[t - 1];
        int segstart_excl;
        if (t < NBLK_E) segstart_excl = 0;
        else if (t < NBLK_E + NBLK_C) segstart_excl = ss[NBLK_E - 1];
        else segstart_excl = ss[NBLK_E + NBLK_C - 1];
        blk_off[t] = excl - segstart_excl;
    }
    if (t == 0) {
        e_starts[N_ENTITIES] = N_EDGES;
        c_starts[N_ITEMS]    = N_INTER;
        r_starts[N_USERS]    = N_INTER;
    }
}

// ---- scan stage C: write starts[key]; transform partial[s][key] in place
// into the (slice,key) cursor start = starts[key] + sum_{s'<s} partial ----
__global__ void scanC_k(int* __restrict__ partial,
                        const int* __restrict__ blk_off,
                        int* __restrict__ e_starts, int* __restrict__ c_starts,
                        int* __restrict__ r_starts) {
    __shared__ int ss[256];
    int b = blockIdx.x, t = threadIdx.x;
    int base = b * CHUNK;
    int tot[THR_OWN];
    int sum = 0;
    if (t < 250) {
        int g = base + t * THR_OWN;
#pragma unroll
        for (int j = 0; j < THR_OWN; ++j) tot[j] = 0;
#pragma unroll
        for (int s = 0; s < NS; ++s) {
            const int* p = partial + (size_t)s * KTOT + g;
#pragma unroll
            for (int j = 0; j < THR_OWN; ++j) tot[j] += p[j];
        }
#pragma unroll
        for (int j = 0; j < THR_OWN; ++j) sum += tot[j];
    }
    ss[t] = sum;
    __syncthreads();
    for (int off = 1; off < 256; off <<= 1) {
        int v = (t >= off) ? ss[t - off] : 0;
        __syncthreads();
        ss[t] += v;
        __syncthreads();
    }
    if (t < 250) {
        int run = blk_off[b] + ((t == 0) ? 0 : ss[t - 1]);
        int* sarr; int ebase;
        if (b < NBLK_E)               { sarr = e_starts; ebase = base; }
        else if (b < NBLK_E + NBLK_C) { sarr = c_starts; ebase = base - NBLK_E * CHUNK; }
        else                          { sarr = r_starts; ebase = base - (NBLK_E + NBLK_C) * CHUNK; }
        int gl = ebase + t * THR_OWN;
        int gg = base + t * THR_OWN;
        for (int j = 0; j < THR_OWN; ++j) {
            sarr[gl + j] = run;
            int cur = run;
#pragma unroll
            for (int s = 0; s < NS; ++s) {
                int idx = s * KTOT + gg + j;
                int v = partial[idx];
                partial[idx] = cur;
                cur += v;
            }
            run = cur;
        }
    }
}

// ---- merged scatter: ZERO atomics. pos = cursor[s][key] + rank[i].
// Blocks [0,SB) edge role, [SB,2SB) inter role; each half keeps XCD
// key-range partitioning (SB % 8 == 0 preserves blockIdx&7 mapping).
// Independent roles overlap -> combined time ~ max, not sum. ----
__global__ void scatter_all_k(const int* __restrict__ head,
                              const int* __restrict__ packed,
                              const unsigned short* __restrict__ rank_e,
                              const int* __restrict__ mcol,
                              const int* __restrict__ mrow,
                              const unsigned short* __restrict__ rank_c,
                              const unsigned short* __restrict__ rank_r,
                              const int* __restrict__ partial,
                              int* __restrict__ e_sorted,
                              int* __restrict__ i_srow, int* __restrict__ i_scol) {
    if (blockIdx.x < SB) {
        int xcd = blockIdx.x & 7;
        int slot = blockIdx.x >> 3;
        int nslot = SB >> 3;
        int lo = xcd * (N_ENTITIES / 8);
        int hi = lo + (N_ENTITIES / 8);
        for (int i = slot * blockDim.x + threadIdx.x; i < N_EDGES;
             i += nslot * blockDim.x) {
            int h = __builtin_nontemporal_load(&head[i]);
            if (h >= lo && h < hi) {
                int s = i / (N_EDGES / NS);
                int pos = partial[(size_t)s * KTOT + h]
                        + (int)__builtin_nontemporal_load(&rank_e[i]);
                e_sorted[pos] = __builtin_nontemporal_load(&packed[i]);
            }
        }
    } else {
        int b2 = blockIdx.x - SB;
        int xcd = b2 & 7;
        int slot = b2 >> 3;
        int nslot = SB >> 3;
        int clo = xcd * (N_ITEMS / 8), chi = clo + (N_ITEMS / 8);
        int rlo = xcd * (N_USERS / 8), rhi = rlo + (N_USERS / 8);
        for (int i = slot * blockDim.x + threadIdx.x; i < N_INTER;
             i += nslot * blockDim.x) {
            int c = __builtin_nontemporal_load(&mcol[i]);
            int r = __builtin_nontemporal_load(&mrow[i]);
            int s = i / (N_INTER / NS);
            if (c >= clo && c < chi) {
                int pos = partial[(size_t)s * KTOT + N_ENTITIES + c]
                        + (int)__builtin_nontemporal_load(&rank_c[i]);
                i_srow[pos] = r;
            }
            if (r >= rlo && r < rhi) {
                int pos = partial[(size_t)s * KTOT + N_ENTITIES + N_ITEMS + r]
                        + (int)__builtin_nontemporal_load(&rank_r[i]);
                i_scol[pos] = c;
            }
        }
    }
}

// ---- merged aggregation, QUARTER-PER-ROW: each 16-lane quarter owns one
// row entirely (16 lanes x ushort4 = full 128B bf16 row). Per-quarter loop
// divergence is safe: every __shfl source (lane&48)|k stays inside the
// quarter's own (active) lanes. ----
__global__ void agg_all_k(const ushort4* __restrict__ ent_bf,
                          const float* __restrict__ ent0f,
                          const float* __restrict__ wrel,
                          const int* __restrict__ es,
                          const int* __restrict__ e_sorted,
                          float* __restrict__ agg,
                          ushort4* __restrict__ ent_cur_bf,
                          float* __restrict__ ent_res,
                          const ushort4* __restrict__ usr_bf,
                          const int* __restrict__ cs,
                          const int* __restrict__ i_srow,
                          float* __restrict__ iint,
                          int first) {
    int lane = threadIdx.x & 63;
    int q = lane >> 4, ql = lane & 15;
    int qb = lane & 48;
    if (blockIdx.x < EB) {
        __shared__ float4 wl4[32 * 16];   // 32 relations x 16 float4 (fp32)
        for (int idx = threadIdx.x; idx < 512; idx += 256)
            wl4[idx] = ((const float4*)wrel)[idx];
        __syncthreads();
        int qid = (blockIdx.x * 4 + (threadIdx.x >> 6)) * 4 + q;
        int nq = EB * 16;
        for (int h = qid; h < N_ENTITIES; h += nq) {
            int beg = es[h], end = es[h + 1];
            float4 a0 = {0, 0, 0, 0}, a1 = {0, 0, 0, 0};
            for (int j0 = beg; j0 < end; j0 += 16) {
                int p = (j0 + ql < end) ? e_sorted[j0 + ql] : 0;
                int mm = end - j0; if (mm > 16) mm = 16;
                int k = 0;
                for (; k + 1 < mm; k += 2) {
                    int p0 = __shfl(p, qb | k, 64);
                    int p1 = __shfl(p, qb | (k + 1), 64);
                    float4 e0 = bf2f4(ent_bf[(size_t)(p0 & 0x3FFFF) * 16 + ql]);
                    float4 w0 = wl4[((p0 >> 18) << 4) + ql];
                    float4 e1 = bf2f4(ent_bf[(size_t)(p1 & 0x3FFFF) * 16 + ql]);
                    float4 w1 = wl4[((p1 >> 18) << 4) + ql];
                    a0.x = fmaf(e0.x, w0.x, a0.x); a0.y = fmaf(e0.y, w0.y, a0.y);
                    a0.z = fmaf(e0.z, w0.z, a0.z); a0.w = fmaf(e0.w, w0.w, a0.w);
                    a1.x = fmaf(e1.x, w1.x, a1.x); a1.y = fmaf(e1.y, w1.y, a1.y);
                    a1.z = fmaf(e1.z, w1.z, a1.z); a1.w = fmaf(e1.w, w1.w, a1.w);
                }
                if (k < mm) {
                    int p0 = __shfl(p, qb | k, 64);
                    float4 e0 = bf2f4(ent_bf[(size_t)(p0 & 0x3FFFF) * 16 + ql]);
                    float4 w0 = wl4[((p0 >> 18) << 4) + ql];
                    a0.x = fmaf(e0.x, w0.x, a0.x); a0.y = fmaf(e0.y, w0.y, a0.y);
                    a0.z = fmaf(e0.z, w0.z, a0.z); a0.w = fmaf(e0.w, w0.w, a0.w);
                }
            }
            float4 v; v.x = a0.x + a1.x; v.y = a0.y + a1.y;
            v.z = a0.z + a1.z; v.w = a0.w + a1.w;
            if (h < N_ITEMS) {
                int d = end - beg;
                float inv = 1.0f / (float)(d > 0 ? d : 1);
                float4 o; o.x = v.x * inv; o.y = v.y * inv;
                o.z = v.z * inv; o.w = v.w * inv;
                ((float4*)agg)[(size_t)h * 16 + ql] = o;
            } else {
                // l2norm(mean) == l2norm(sum): scale-invariant
                float s = qsum16(fmaf(v.x, v.x, fmaf(v.y, v.y, fmaf(v.z, v.z, v.w * v.w))));
                float inv = 1.0f / fmaxf(sqrtf(s), 1e-12f);
                float4 vn; vn.x = v.x * inv; vn.y = v.y * inv;
                vn.z = v.z * inv; vn.w = v.w * inv;
                size_t o4 = (size_t)h * 16 + ql;
                if (first) {
                    ent_cur_bf[o4] = f2bf4(vn);
                    float4 b = ((const float4*)ent0f)[o4];
                    b.x += vn.x; b.y += vn.y; b.z += vn.z; b.w += vn.w;
                    ((float4*)ent_res)[o4] = b;
                } else {
                    float4 r = ((float4*)ent_res)[o4];
                    r.x += vn.x; r.y += vn.y; r.z += vn.z; r.w += vn.w;
                    ((float4*)ent_res)[o4] = r;
                }
            }
        }
    } else {
        int qid = ((blockIdx.x - EB) * 4 + (threadIdx.x >> 6)) * 4 + q;
        int nq = IB * 16;
        for (int c = qid; c < N_ITEMS; c += nq) {
            int beg = cs[c], end = cs[c + 1];
            float4 a0 = {0, 0, 0, 0}, a1 = {0, 0, 0, 0};
            for (int j0 = beg; j0 < end; j0 += 16) {
                int p = (j0 + ql < end) ? i_srow[j0 + ql] : 0;
                int mm = end - j0; if (mm > 16) mm = 16;
                int k = 0;
                for (; k + 1 < mm; k += 2) {
                    int p0 = __shfl(p, qb | k, 64);
                    int p1 = __shfl(p, qb | (k + 1), 64);
                    float4 u0 = bf2f4(usr_bf[(size_t)p0 * 16 + ql]);
                    float4 u1 = bf2f4(usr_bf[(size_t)p1 * 16 + ql]);
                    a0.x += u0.x; a0.y += u0.y; a0.z += u0.z; a0.w += u0.w;
                    a1.x += u1.x; a1.y += u1.y; a1.z += u1.z; a1.w += u1.w;
                }
                if (k < mm) {
                    int p0 = __shfl(p, qb | k, 64);
                    float4 u0 = bf2f4(usr_bf[(size_t)p0 * 16 + ql]);
                    a0.x += u0.x; a0.y += u0.y; a0.z += u0.z; a0.w += u0.w;
                }
            }
            float4 v; v.x = a0.x + a1.x; v.y = a0.y + a1.y;
            v.z = a0.z + a1.z; v.w = a0.w + a1.w;
            int d = end - beg;
            float inv = 1.0f / (float)(d > 0 ? d : 1);
            float4 o; o.x = v.x * inv; o.y = v.y * inv;
            o.z = v.z * inv; o.w = v.w * inv;
            ((float4*)iint)[(size_t)c * 16 + ql] = o;
        }
    }
}

// ---- fuse: register-tiled LDS GEMM, y = [kg|ii] @ [g1|g2]^T ----
// outputs: ifus_bf + ent_cur_bf (bf16 gather tables), fp32 residuals.
__global__ void fuse_k(const float* __restrict__ agg,
                       const float* __restrict__ iint,
                       const float* __restrict__ g1,
                       const float* __restrict__ g2,
                       const float* __restrict__ ent0,
                       unsigned short* __restrict__ ifus_bf,
                       unsigned short* __restrict__ ent_cur_bf,
                       float* __restrict__ ent_res,
                       float* __restrict__ kg_res,
                       float* __restrict__ int_res,
                       int first) {
    __shared__ float A[FT * FPAD];   // [item][k]: k 0..63 = kg, 64..127 = ii
    __shared__ float B[64 * FPAD];   // [j][k]:    k 0..63 = g1, 64..127 = g2
    int t = threadIdx.x;
    int ibase = blockIdx.x * FT;

    {
        const float4* g14 = (const float4*)g1;
        const float4* g24 = (const float4*)g2;
        const float4* a4 = (const float4*)(agg + (size_t)ibase * D);
        const float4* i4 = (const float4*)(iint + (size_t)ibase * D);
        for (int idx = t; idx < 1024; idx += 256) {
            int r = idx >> 4, kq = idx & 15;
            ((float4*)&B[r * FPAD])[kq]      = g14[idx];
            ((float4*)&B[r * FPAD + 64])[kq] = g24[idx];
            ((float4*)&A[r * FPAD])[kq]      = a4[idx];   // benign OOB read on
            ((float4*)&A[r * FPAD + 64])[kq] = i4[idx];   // tail tile (ws mem)
        }
    }
    __syncthreads();

    int ti = t >> 4, tj = t & 15;

    float y[4][4] = {};
    for (int k = 0; k < 128; k += 4) {
        float4 av[4], bv[4];
#pragma unroll
        for (int a = 0; a < 4; ++a) av[a] = *(const float4*)&A[(ti + 16 * a) * FPAD + k];
#pragma unroll
        for (int b = 0; b < 4; ++b) bv[b] = *(const float4*)&B[(tj + 16 * b) * FPAD + k];
#pragma unroll
        for (int a = 0; a < 4; ++a)
#pragma unroll
            for (int b = 0; b < 4; ++b) {
                y[a][b] = fmaf(av[a].x, bv[b].x, y[a][b]);
                y[a][b] = fmaf(av[a].y, bv[b].y, y[a][b]);
                y[a][b] = fmaf(av[a].z, bv[b].z, y[a][b]);
                y[a][b] = fmaf(av[a].w, bv[b].w, y[a][b]);
            }
    }

    float fus[4][4], kg[4][4], ii[4][4];
    float sf[4], sk[4], si[4];
#pragma unroll
    for (int a = 0; a < 4; ++a) { sf[a] = 0.f; sk[a] = 0.f; si[a] = 0.f; }
#pragma unroll
    for (int a = 0; a < 4; ++a) {
        int i = ti + 16 * a;
#pragma unroll
        for (int b = 0; b < 4; ++b) {
            int j = tj + 16 * b;
            float K = A[i * FPAD + j];
            float I = A[i * FPAD + 64 + j];
            float gi = 1.0f / (1.0f + __expf(-y[a][b]));
            float f = gi * K + (1.0f - gi) * I;
            fus[a][b] = f; kg[a][b] = K; ii[a][b] = I;
            sf[a] = fmaf(f, f, sf[a]);
            sk[a] = fmaf(K, K, sk[a]);
            si[a] = fmaf(I, I, si[a]);
        }
    }
#pragma unroll
    for (int off = 1; off < 16; off <<= 1) {
#pragma unroll
        for (int a = 0; a < 4; ++a) {
            sf[a] += __shfl_xor(sf[a], off, 64);
            sk[a] += __shfl_xor(sk[a], off, 64);
            si[a] += __shfl_xor(si[a], off, 64);
        }
    }

#pragma unroll
    for (int a = 0; a < 4; ++a) {
        int i = ibase + ti + 16 * a;
        if (i < N_ITEMS) {
            float nf = 1.0f / fmaxf(sqrtf(sf[a]), 1e-12f);
            float nk = 1.0f / fmaxf(sqrtf(sk[a]), 1e-12f);
            float ni = 1.0f / fmaxf(sqrtf(si[a]), 1e-12f);
#pragma unroll
            for (int b = 0; b < 4; ++b) {
                size_t o = (size_t)i * D + tj + 16 * b;
                float f = fus[a][b];
                ifus_bf[o] = f2bf(f);
                float fn = f * nf;
                ent_cur_bf[o] = f2bf(fn);
                if (first) {
                    ent_res[o] = ent0[o] + fn;
                    kg_res[o]  = kg[a][b] * nk;
                    int_res[o] = ii[a][b] * ni;
                } else {
                    ent_res[o] += fn;
                    kg_res[o]  += kg[a][b] * nk;
                    int_res[o] += ii[a][b] * ni;
                }
            }
        }
    }
}

// ---- per-user segment sum of item_fusion + l2 norm (quarter-per-row) ----
__global__ void user_agg_k(const ushort4* __restrict__ ifus_bf,
                           const int* __restrict__ rs,
                           const int* __restrict__ i_scol,
                           const float* __restrict__ usr0,
                           ushort4* __restrict__ usr_cur_bf,
                           float* __restrict__ usr_res,
                           int first) {
    const float4* u04 = (const float4*)usr0;
    int lane = threadIdx.x & 63;
    int q = lane >> 4, ql = lane & 15;
    int qb = lane & 48;
    int qid = (blockIdx.x * (blockDim.x >> 6) + (threadIdx.x >> 6)) * 4 + q;
    int nq = gridDim.x * (blockDim.x >> 6) * 4;
    for (int u = qid; u < N_USERS; u += nq) {
        int beg = rs[u], end = rs[u + 1];
        float4 a0 = {0, 0, 0, 0}, a1 = {0, 0, 0, 0};
        for (int j0 = beg; j0 < end; j0 += 16) {
            int p = (j0 + ql < end) ? i_scol[j0 + ql] : 0;
            int mm = end - j0; if (mm > 16) mm = 16;
            int k = 0;
            for (; k + 1 < mm; k += 2) {
                int p0 = __shfl(p, qb | k, 64);
                int p1 = __shfl(p, qb | (k + 1), 64);
                float4 u0 = bf2f4(ifus_bf[(size_t)p0 * 16 + ql]);
                float4 u1 = bf2f4(ifus_bf[(size_t)p1 * 16 + ql]);
                a0.x += u0.x; a0.y += u0.y; a0.z += u0.z; a0.w += u0.w;
                a1.x += u1.x; a1.y += u1.y; a1.z += u1.z; a1.w += u1.w;
            }
            if (k < mm) {
                int p0 = __shfl(p, qb | k, 64);
                float4 u0 = bf2f4(ifus_bf[(size_t)p0 * 16 + ql]);
                a0.x += u0.x; a0.y += u0.y; a0.z += u0.z; a0.w += u0.w;
            }
        }
        float4 v; v.x = a0.x + a1.x; v.y = a0.y + a1.y;
        v.z = a0.z + a1.z; v.w = a0.w + a1.w;
        float s = qsum16(fmaf(v.x, v.x, fmaf(v.y, v.y, fmaf(v.z, v.z, v.w * v.w))));
        float inv = 1.0f / fmaxf(sqrtf(s), 1e-12f);
        float4 vn; vn.x = v.x * inv; vn.y = v.y * inv;
        vn.z = v.z * inv; vn.w = v.w * inv;
        size_t o4 = (size_t)u * 16 + ql;
        usr_cur_bf[o4] = f2bf4(vn);
        if (first) {
            float4 b = u04[o4];
            b.x += vn.x; b.y += vn.y; b.z += vn.z; b.w += vn.w;
            ((float4*)usr_res)[o4] = b;
        } else {
            float4 r = ((float4*)usr_res)[o4];
            r.x += vn.x; r.y += vn.y; r.z += vn.z; r.w += vn.w;
            ((float4*)usr_res)[o4] = r;
        }
    }
}

extern "C" void kernel_launch(void* const* d_in, const int* in_sizes, int n_in,
                              void* d_out, int out_size, void* d_ws, size_t ws_size,
                              hipStream_t stream) {
    const float* user_emb   = (const float*)d_in[0];
    const float* entity_emb = (const float*)d_in[1];
    const float* wrel       = (const float*)d_in[2];
    const float* g1         = (const float*)d_in[3];
    const float* g2         = (const float*)d_in[4];
    const int*   edge_head  = (const int*)d_in[5];
    const int*   edge_tail  = (const int*)d_in[6];
    const int*   edge_type  = (const int*)d_in[7];
    const int*   mat_row    = (const int*)d_in[8];
    const int*   mat_col    = (const int*)d_in[9];

    const size_t ENT_SZ = (size_t)N_ENTITIES * D;  //  9.6M
    const size_t USR_SZ = (size_t)N_USERS * D;     // 12.8M
    const size_t ITM_SZ = (size_t)N_ITEMS * D;     //  3.2M

    float* out     = (float*)d_out;
    float* ent_res = out;
    float* usr_res = out + ENT_SZ;
    float* kg_res  = out + ENT_SZ + USR_SZ;
    float* int_res = out + ENT_SZ + USR_SZ + ITM_SZ;

    // workspace layout (bf16 gather tables + fp32 staging)
    char* p = (char*)d_ws;
    unsigned short* ent_cur_bf = (unsigned short*)p; p += ENT_SZ * 2;  // 19.2 MB
    unsigned short* usr_cur_bf = (unsigned short*)p; p += USR_SZ * 2;  // 25.6 MB
    unsigned short* ent0_bf    = (unsigned short*)p; p += ENT_SZ * 2;  // 19.2 MB
    unsigned short* usr0_bf    = (unsigned short*)p; p += USR_SZ * 2;  // 25.6 MB
    float* agg  = (float*)p; p += ITM_SZ * 4;                          // 12.8 MB
    float* iint = (float*)p; p += ITM_SZ * 4;                          // 12.8 MB
    unsigned short* ifus_bf = (unsigned short*)p; p += ITM_SZ * 2;     //  6.4 MB
    int* e_starts = (int*)p; p += (N_ENTITIES + 1) * 4;
    int* c_starts = (int*)p; p += (N_ITEMS + 1) * 4;
    int* r_starts = (int*)p; p += (N_USERS + 1) * 4;
    unsigned short* rank_e = (unsigned short*)p; p += (size_t)N_EDGES * 2; // 4 MB
    unsigned short* rank_c = (unsigned short*)p; p += (size_t)N_INTER * 2; // 2 MB
    unsigned short* rank_r = (unsigned short*)p; p += (size_t)N_INTER * 2; // 2 MB
    p = (char*)(((size_t)p + 15) & ~(size_t)15);
    int* e_sorted = (int*)p; p += (size_t)N_EDGES * 4;                 //  8 MB
    int* i_srow   = (int*)p; p += (size_t)N_INTER * 4;                 //  4 MB
    int* i_scol   = (int*)p; p += (size_t)N_INTER * 4;                 //  4 MB
    int* packed   = (int*)p; p += (size_t)N_EDGES * 4;                 //  8 MB
    int* blk_sums = (int*)p; p += NBLK_TOT * 4;
    int* blk_off  = (int*)p; p += NBLK_TOT * 4;
    // partial[NS][KTOT] = 25.6 MB aliases agg+iint (exactly 25.6 MB): CSR
    // build completes before agg/iint are first written in the hop loop.
    int* partial = (int*)agg;

    // merged prep + hist (independent roles overlap; ZERO global atomics)
    hist_prep_k<<<HB + PB, HT, 0, stream>>>(edge_head, mat_col, mat_row,
                                            partial, rank_e, rank_c, rank_r,
                                            (const float4*)entity_emb,
                                            (ushort4*)ent0_bf, (int)(ENT_SZ / 4),
                                            (const float4*)user_emb,
                                            (ushort4*)usr0_bf, (int)(USR_SZ / 4),
                                            edge_tail, edge_type, packed);
    scanA_k<<<NBLK_TOT, 256, 0, stream>>>(partial, blk_sums);
    scanB_k<<<1, 512, 0, stream>>>(blk_sums, blk_off, e_starts, c_starts, r_starts);
    scanC_k<<<NBLK_TOT, 256, 0, stream>>>(partial, blk_off,
                                          e_starts, c_starts, r_starts);
    scatter_all_k<<<2 * SB, 256, 0, stream>>>(edge_head, packed, rank_e,
                                              mat_col, mat_row, rank_c, rank_r,
                                              partial, e_sorted, i_srow, i_scol);

    for (int hop = 0; hop < 2; ++hop) {
        const unsigned short* ent_src = (hop == 0) ? ent0_bf : ent_cur_bf;
        const unsigned short* usr_src = (hop == 0) ? usr0_bf : usr_cur_bf;
        int first = (hop == 0);
        agg_all_k<<<EB + IB, 256, 0, stream>>>((const ushort4*)ent_src, entity_emb,
                                               wrel, e_starts, e_sorted,
                                               agg, (ushort4*)ent_cur_bf, ent_res,
                                               (const ushort4*)usr_src, c_starts,
                                               i_srow, iint, first);
        fuse_k<<<NTILE, 256, 0, stream>>>(agg, iint, g1, g2, entity_emb,
                                          ifus_bf, ent_cur_bf,
                                          ent_res, kg_res, int_res, first);
        user_agg_k<<<2048, 256, 0, stream>>>((const ushort4*)ifus_bf, r_starts,
                                             i_scol, user_emb,
                                             (ushort4*)usr_cur_bf, usr_res, first);
    }
}